// Round 8
// baseline (503.309 us; speedup 1.0000x reference)
//
#include <hip/hip_runtime.h>
#include <math.h>

typedef __bf16 bf16;
typedef __bf16 bf16x8 __attribute__((ext_vector_type(8)));
typedef __bf16 bf16x4 __attribute__((ext_vector_type(4)));
typedef __bf16 bf16x2 __attribute__((ext_vector_type(2)));
typedef float f32x4 __attribute__((ext_vector_type(4)));
typedef short s16x4 __attribute__((ext_vector_type(4)));

// ---------------- constants ----------------
constexpr int Bsz = 8, HIMG = 24, WIMG = 24;
constexpr int Lq = 576;
constexpr int WIDTH = 1024, NCH = 8, CW = 128;
constexpr int NHEADS = 8, HD = 16, HALF = 8;
constexpr float EPS = 1e-6f;
constexpr float LAMINIT = 0.2f;
// 1/sqrt(8) * log2(e): scores exit MFMA in log2 domain -> v_exp_f32 directly
constexpr float QSCALE_E = 0.35355339059327373f * 1.4426950408889634f;
constexpr int ROWS = Bsz * Lq;              // 4608

__device__ __forceinline__ float fexp2(float x) {
#if __has_builtin(__builtin_amdgcn_exp2f)
  return __builtin_amdgcn_exp2f(x);
#else
  return exp2f(x);
#endif
}

// ---------------- workspace byte offsets ----------------
constexpr size_t B_HB    = 0;                        // bf16 h [4608][1024]
constexpr size_t B_G2B   = B_HB    + 9437184;        // bf16 g2 [4608][1024] (MLP out)
constexpr size_t B_ENCB  = B_G2B   + 9437184;        // bf16 enc [640][128]
constexpr size_t B_POSWT = B_ENCB  + 163840;         // bf16 [1024][128]
constexpr size_t B_QKVWT = B_POSWT + 262144;         // bf16 [8][384][128]
constexpr size_t B_OWT   = B_QKVWT + 786432;         // bf16 [8][128][128]
constexpr size_t B_SE    = B_OWT   + 262144;         // f32 [8][1024]
constexpr size_t B_T1    = B_SE    + 32768;          // f32 [8][256] SE hidden
constexpr size_t B_MP    = B_T1    + 8192;           // f32 [8][16][1024] pool partials
constexpr size_t B_RW    = B_MP    + 524288;         // f32 [64]
constexpr size_t B_LAM   = B_RW    + 256;            // f32 [8]
constexpr size_t B_POOL  = B_LAM   + 256;            // phase-shared pool
// pool (pos phase):  POS f32 [640][1024] = 2621440
// pool (MLP phase):  W1T 8388608 | W2T 8388608 | HID bf16 [4608][2048] 18874368 = 35651584
// pool (chan phase): QKV (8ch) 28311552 | DC 9437184 (out-proj IN-PLACE on DC)
// high water: B_POOL + 37748736 ~= 58.7 MB (< 59.4 MB proven in R1)

// ---------------- helpers ----------------
__device__ __forceinline__ float blockReduceSum256(float v, float* red) {
  #pragma unroll
  for (int off = 32; off; off >>= 1) v += __shfl_down(v, off, 64);
  int lane = threadIdx.x & 63, wid = threadIdx.x >> 6;
  if (lane == 0) red[wid] = v;
  __syncthreads();
  float total = 0.f;
  #pragma unroll
  for (int i = 0; i < 4; i++) total += red[i];
  return total;
}
__device__ __forceinline__ float silu(float x) { return x / (1.f + __expf(-x)); }

__device__ __forceinline__ void gl16(const bf16* g, bf16* l) {
  __builtin_amdgcn_global_load_lds(
      (const __attribute__((address_space(1))) void*)g,
      (__attribute__((address_space(3))) void*)l, 16, 0, 0);
}

// v_mfma_f32_16x16x16_bf16 wrapper (A,B = 4 bf16/lane; k = quad*4+j)
__device__ __forceinline__ f32x4 mfma16(bf16x4 a, bf16x4 b, f32x4 c) {
#if __has_builtin(__builtin_amdgcn_mfma_f32_16x16x16bf16_1k)
  union { bf16x4 h; s16x4 s; } ua, ub;
  ua.h = a; ub.h = b;
  return __builtin_amdgcn_mfma_f32_16x16x16bf16_1k(ua.s, ub.s, c, 0, 0, 0);
#else
  f32x4 d = c;
  asm volatile("v_mfma_f32_16x16x16_bf16 %0, %1, %2, %0"
               : "+v"(d) : "v"(a), "v"(b));
  return d;
#endif
}

// ---------------- cast+transpose: W fp32 [K][N] -> Wt bf16 [N][K] ----------------
__global__ __launch_bounds__(256) void k_tcast(const float* __restrict__ W,
    bf16* __restrict__ Wt, int K, int N) {
  __shared__ float t[32][33];
  int n0 = blockIdx.x * 32, k0 = blockIdx.y * 32;
  long zo = (long)blockIdx.z * K * N;
  int tid = threadIdx.x;
  int r = tid >> 3, c4 = (tid & 7) * 4;
  const float4 v = *(const float4*)(W + zo + (long)(k0 + r) * N + n0 + c4);
  t[c4 + 0][r] = v.x; t[c4 + 1][r] = v.y; t[c4 + 2][r] = v.z; t[c4 + 3][r] = v.w;
  __syncthreads();
  bf16* dst = Wt + zo + (long)(n0 + r) * K + k0 + c4;
  dst[0] = (bf16)t[r][c4 + 0]; dst[1] = (bf16)t[r][c4 + 1];
  dst[2] = (bf16)t[r][c4 + 2]; dst[3] = (bf16)t[r][c4 + 3];
}

// ---------------- positional encoding (bf16 out) ----------------
__global__ void k_enc_b(const float* __restrict__ fh, const float* __restrict__ fw,
                        const float* __restrict__ ph, const float* __restrict__ pw,
                        bf16* __restrict__ enc) {
  int idx = blockIdx.x * blockDim.x + threadIdx.x;
  if (idx >= Lq * 128) return;
  int l = idx >> 7, c = idx & 127;
  int hh = l / WIMG, ww = l % WIMG;
  float v;
  if (c < 64) {
    int f = c & 31;
    float fr = log1pf(__expf(fh[f])) * 10.f;
    float a = (hh / (float)HIMG) * fr + ph[f];
    v = (c < 32) ? sinf(a) : cosf(a);
  } else {
    int f = c & 31;
    float fr = log1pf(__expf(fw[f])) * 10.f;
    float a = (ww / (float)WIMG) * fr + pw[f];
    v = (c < 96) ? sinf(a) : cosf(a);
  }
  enc[idx] = (bf16)v;
}

// ---------------- bf16 MFMA GEMM 128x128 ----------------
template <int ACT, int OUTBF>
__global__ __launch_bounds__(256) void gemm_bt(
    const bf16* __restrict__ A, int lda, long aZs,
    const bf16* __restrict__ Bt, long bZs,
    const float* __restrict__ bias, int biasZs,
    void* __restrict__ Cv, int ldc, long cZs,
    int M, int N, int K) {
  __shared__ bf16 As[128 * 32];
  __shared__ bf16 Bs[128 * 32];
  int tid = threadIdx.x;
  int m0 = blockIdx.y * 128, n0 = blockIdx.x * 128;
  int z = blockIdx.z;
  const bf16* Ab = A + (long)z * aZs;
  const bf16* Bb = Bt + (long)z * bZs;
  f32x4 acc[4][4] = {};
  int wv = tid >> 6, lane = tid & 63;
  int wrow = (wv >> 1) * 64, wcol = (wv & 1) * 64;
  int lm = lane & 15, lq = lane >> 4;
  const bf16* ag = Ab + (long)(m0 + (tid >> 2)) * lda + (tid & 3) * 8;
  const bf16* bg = Bb + (long)(n0 + (tid >> 2)) * K + (tid & 3) * 8;
  bf16* asd = As + tid * 8;
  bf16* bsd = Bs + tid * 8;
  for (int k0 = 0; k0 < K; k0 += 32) {
    gl16(ag + k0, asd);
    gl16(ag + k0 + 64L * lda, asd + 2048);
    gl16(bg + k0, bsd);
    gl16(bg + k0 + 64L * K, bsd + 2048);
    __syncthreads();
    bf16x8 af[4], bfr[4];
    #pragma unroll
    for (int i = 0; i < 4; i++) {
      af[i]  = *(const bf16x8*)(As + (wrow + i * 16 + lm) * 32 + lq * 8);
      bfr[i] = *(const bf16x8*)(Bs + (wcol + i * 16 + lm) * 32 + lq * 8);
    }
    #pragma unroll
    for (int i = 0; i < 4; i++)
      #pragma unroll
      for (int j = 0; j < 4; j++)
        acc[i][j] = __builtin_amdgcn_mfma_f32_16x16x32_bf16(af[i], bfr[j], acc[i][j], 0, 0, 0);
    __syncthreads();
  }
  long cz = (long)z * cZs;
  const float* bz = bias ? bias + (long)z * biasZs : nullptr;
  #pragma unroll
  for (int i = 0; i < 4; i++) {
    int row = m0 + wrow + i * 16 + lq * 4;
    #pragma unroll
    for (int j = 0; j < 4; j++) {
      int col = n0 + wcol + j * 16 + lm;
      float bv = bz ? bz[col] : 0.f;
      #pragma unroll
      for (int r = 0; r < 4; r++) {
        float v = acc[i][j][r] + bv;
        if (ACT == 1) v = silu(v);
        long off = cz + (long)(row + r) * ldc + col;
        if (OUTBF) ((bf16*)Cv)[off] = (bf16)v;
        else       ((float*)Cv)[off] = v;
      }
    }
  }
}

// ---------------- bf16 MFMA GEMM 64x128 tile ----------------
template <int ACT, int OUTBF, int ACC>
__global__ __launch_bounds__(256) void gemm64(
    const bf16* __restrict__ A, int lda, long aZs,
    const bf16* __restrict__ Bt, int ldb, long bZs,
    const float* __restrict__ bias, int biasZs,
    void* __restrict__ Cv, int ldc, long cZs,
    int M, int N, int K) {
  __shared__ bf16 As[64 * 32];
  __shared__ bf16 Bs[128 * 32];
  int tid = threadIdx.x;
  int m0 = blockIdx.y * 64, n0 = blockIdx.x * 128;
  int z = blockIdx.z;
  const bf16* Ab = A + (long)z * aZs;
  const bf16* Bb = Bt + (long)z * bZs;
  f32x4 acc[4][2] = {};
  int wv = tid >> 6, lane = tid & 63;
  int lm = lane & 15, lq = lane >> 4;
  int wcol = wv * 32;
  const bf16* ag = Ab + (long)(m0 + (tid >> 2)) * lda + (tid & 3) * 8;
  const bf16* bg = Bb + (long)(n0 + (tid >> 2)) * ldb + (tid & 3) * 8;
  bf16* asd = As + tid * 8;
  bf16* bsd = Bs + tid * 8;
  for (int k0 = 0; k0 < K; k0 += 32) {
    if (tid < 256) gl16(ag + k0, asd);
    gl16(bg + k0, bsd);
    gl16(bg + k0 + 64L * ldb, bsd + 2048);
    __syncthreads();
    bf16x8 af[4], bfr[2];
    #pragma unroll
    for (int i = 0; i < 4; i++)
      af[i] = *(const bf16x8*)(As + (i * 16 + lm) * 32 + lq * 8);
    #pragma unroll
    for (int j = 0; j < 2; j++)
      bfr[j] = *(const bf16x8*)(Bs + (wcol + j * 16 + lm) * 32 + lq * 8);
    #pragma unroll
    for (int i = 0; i < 4; i++)
      #pragma unroll
      for (int j = 0; j < 2; j++)
        acc[i][j] = __builtin_amdgcn_mfma_f32_16x16x32_bf16(af[i], bfr[j], acc[i][j], 0, 0, 0);
    __syncthreads();
  }
  long cz = (long)z * cZs;
  const float* bz = bias ? bias + (long)z * biasZs : nullptr;
  #pragma unroll
  for (int i = 0; i < 4; i++) {
    int row = m0 + i * 16 + lq * 4;
    #pragma unroll
    for (int j = 0; j < 2; j++) {
      int col = n0 + wcol + j * 16 + lm;
      float bv = bz ? bz[col] : 0.f;
      #pragma unroll
      for (int r = 0; r < 4; r++) {
        float v = acc[i][j][r] + bv;
        long off = cz + (long)(row + r) * ldc + col;
        if (ACC) v += (float)((bf16*)Cv)[off];
        if (ACT == 1) v = silu(v);
        if (OUTBF) ((bf16*)Cv)[off] = (bf16)v;
        else       ((float*)Cv)[off] = v;
      }
    }
  }
}

// ---------------- embed + rmsnorm -> bf16 h ----------------
__global__ __launch_bounds__(256) void k_embed(const float* __restrict__ x,
    const float* __restrict__ emb, const float* __restrict__ pos,
    const float* __restrict__ nw, bf16* __restrict__ h) {
  __shared__ float red[4];
  int row = blockIdx.x;
  int l = row % Lq;
  int xi = (int)(x[row] * 255.f);
  xi = min(max(xi, 0), 255);
  const float* er = emb + (long)xi * WIDTH;
  const float* pr = pos + (long)l * WIDTH;
  int c0 = threadIdx.x * 4;
  float v[4]; float ss = 0.f;
  #pragma unroll
  for (int i = 0; i < 4; i++) { v[i] = er[c0 + i] + pr[c0 + i]; ss += v[i] * v[i]; }
  ss = blockReduceSum256(ss, red);
  float r = rsqrtf(ss / WIDTH + EPS);
  bf16* hr = h + (long)row * WIDTH;
  #pragma unroll
  for (int i = 0; i < 4; i++) hr[c0 + i] = (bf16)(v[i] * r * nw[c0 + i]);
}

// ---------------- mean over L, phase 1: 16 partials per b -> MP[b][16][1024] --------
__global__ void k_meanl_p(const bf16* __restrict__ h, float* __restrict__ part) {
  int lp = blockIdx.x, b = blockIdx.y, t = threadIdx.x;
  const bf16* p = h + ((long)b * Lq + (long)lp * 36) * WIDTH + t * 4;
  float a0 = 0, a1 = 0, a2 = 0, a3 = 0;
  for (int l = 0; l < 36; l++) {
    bf16x4 v = *(const bf16x4*)(p + (long)l * WIDTH);
    a0 += (float)v[0]; a1 += (float)v[1]; a2 += (float)v[2]; a3 += (float)v[3];
  }
  float* dst = part + ((long)b * 16 + lp) * WIDTH + t * 4;
  dst[0] = a0; dst[1] = a1; dst[2] = a2; dst[3] = a3;
}

// ---------------- SE phase 1 (reads 16 MP partials): t1 = silu(mean @ w1 + b1) ------
__global__ __launch_bounds__(256) void k_se1(const float* __restrict__ part,
    const float* __restrict__ w1, const float* __restrict__ b1,
    float* __restrict__ t1) {
  __shared__ float sv[1024];
  __shared__ float red[256];
  int jb = blockIdx.x, b = blockIdx.y, t = threadIdx.x;
  for (int c = t; c < 1024; c += 256) {
    float a = 0.f;
    #pragma unroll
    for (int lp = 0; lp < 16; lp++) a += part[((long)b * 16 + lp) * 1024 + c];
    sv[c] = a * (1.f / 576.f);
  }
  __syncthreads();
  int j = t & 7, pt = t >> 3;
  int j0 = jb * 8;
  float acc = 0.f;
  int c0 = pt * 32;
  #pragma unroll 8
  for (int c = c0; c < c0 + 32; c++) acc += sv[c] * w1[c * 256 + j0 + j];
  red[t] = acc;
  __syncthreads();
  if (t < 8) {
    float a = b1[j0 + t];
    #pragma unroll
    for (int p = 0; p < 32; p++) a += red[p * 8 + t];
    t1[b * 256 + j0 + t] = silu(a);
  }
}

// ---------------- SE phase 2: s = sigmoid(t1 @ w2 + b2) ----------------
__global__ __launch_bounds__(256) void k_se2(const float* __restrict__ t1,
    const float* __restrict__ w2, const float* __restrict__ b2,
    float* __restrict__ s) {
  __shared__ float red[256];
  int jb = blockIdx.x, b = blockIdx.y, t = threadIdx.x;
  int j = t & 31, pt = t >> 5;
  int j0 = jb * 32;
  const float* tb = t1 + b * 256;
  float acc = 0.f;
  int c0 = pt * 32;
  #pragma unroll 8
  for (int c = c0; c < c0 + 32; c++) acc += tb[c] * w2[c * 1024 + j0 + j];
  red[t] = acc;
  __syncthreads();
  if (t < 32) {
    float a = b2[j0 + t];
    #pragma unroll
    for (int p = 0; p < 8; p++) a += red[p * 32 + t];
    s[b * 1024 + j0 + t] = 1.f / (1.f + __expf(-a));
  }
}

// ---------------- mix: h += rmsnorm(h*(s-1), mw)  (bf16 h) ----------------
__global__ __launch_bounds__(256) void k_mix_b(bf16* __restrict__ h,
    const float* __restrict__ s, const float* __restrict__ mw) {
  __shared__ float red[4];
  int row = blockIdx.x;
  int b = row / Lq;
  bf16* hr = h + (long)row * WIDTH;
  const float* sb = s + b * WIDTH;
  int c0 = threadIdx.x * 4;
  float hv[4], y[4]; float ss = 0.f;
  #pragma unroll
  for (int i = 0; i < 4; i++) {
    hv[i] = (float)hr[c0 + i];
    y[i] = hv[i] * (sb[c0 + i] - 1.f); ss += y[i] * y[i];
  }
  ss = blockReduceSum256(ss, red);
  float r = rsqrtf(ss / WIDTH + EPS);
  #pragma unroll
  for (int i = 0; i < 4; i++) hr[c0 + i] = (bf16)(hv[i] + y[i] * r * mw[c0 + i]);
}

// ---------------- h += rmsnorm(g, mw) (bf16) ----------------
__global__ __launch_bounds__(256) void k_addnorm_b(bf16* __restrict__ h,
    const bf16* __restrict__ g, const float* __restrict__ mw) {
  __shared__ float red[4];
  int row = blockIdx.x;
  bf16* hr = h + (long)row * WIDTH;
  const bf16* gr = g + (long)row * WIDTH;
  int c0 = threadIdx.x * 4;
  float y[4]; float ss = 0.f;
  #pragma unroll
  for (int i = 0; i < 4; i++) { y[i] = (float)gr[c0 + i]; ss += y[i] * y[i]; }
  ss = blockReduceSum256(ss, red);
  float r = rsqrtf(ss / WIDTH + EPS);
  #pragma unroll
  for (int i = 0; i < 4; i++)
    hr[c0 + i] = (bf16)((float)hr[c0 + i] + y[i] * r * mw[c0 + i]);
}

// ---------------- router + lambdas (reads 16 MP partials), one block per b ---------
__global__ __launch_bounds__(256) void k_router(const float* __restrict__ part,
    const float* __restrict__ rwgt, const float* __restrict__ rb,
    const float* __restrict__ lq1, const float* __restrict__ lk1,
    const float* __restrict__ lq2, const float* __restrict__ lk2,
    float* __restrict__ rw, float* __restrict__ lam) {
  __shared__ float sv[1024];
  __shared__ float red[256];
  __shared__ float lg[8];
  int b = blockIdx.x, t = threadIdx.x;
  for (int c = t; c < 1024; c += 256) {
    float a = 0.f;
    #pragma unroll
    for (int lp = 0; lp < 16; lp++) a += part[((long)b * 16 + lp) * 1024 + c];
    sv[c] = a * (1.f / 576.f);
  }
  __syncthreads();
  int j = t & 7, pt = t >> 3;
  float acc = 0.f;
  int c0 = pt * 32;
  #pragma unroll 8
  for (int c = c0; c < c0 + 32; c++) acc += sv[c] * rwgt[c * 8 + j];
  red[t] = acc;
  __syncthreads();
  if (t < 8) {
    float a = rb[t];
    for (int p = 0; p < 32; p++) a += red[p * 8 + t];
    lg[t] = a;
  }
  __syncthreads();
  if (t == 0) {
    float v[8]; bool sel[8];
    #pragma unroll
    for (int i = 0; i < 8; i++) { v[i] = lg[i]; sel[i] = false; }
    int idxs[4]; float vals[4];
    for (int s = 0; s < 4; s++) {
      int bi = -1; float bv = -1e30f;
      for (int i = 0; i < 8; i++) if (!sel[i] && v[i] > bv) { bv = v[i]; bi = i; }
      sel[bi] = true; idxs[s] = bi; vals[s] = bv;
    }
    float m = vals[0], den = 0.f, e[4];
    for (int s = 0; s < 4; s++) { e[s] = __expf(vals[s] - m); den += e[s]; }
    for (int i = 0; i < 8; i++) rw[b * 8 + i] = 0.f;
    for (int s = 0; s < 4; s++) rw[b * 8 + idxs[s]] = e[s] / den;
  }
  if (b == 0 && t >= 8 && t < 16) {
    int c = t - 8;
    float d1 = 0.f, d2 = 0.f;
    for (int i = 0; i < 8; i++) {
      d1 += lq1[c * 8 + i] * lk1[c * 8 + i];
      d2 += lq2[c * 8 + i] * lk2[c * 8 + i];
    }
    lam[c] = __expf(d1) - __expf(d2) + LAMINIT;
  }
}

// ---------------- K rmsnorm in place in QKV (per 8-elem half) ----------------
__global__ __launch_bounds__(256) void k_knorm(bf16* __restrict__ qkv,
    const float* __restrict__ kn) {
  int idx = blockIdx.x * 256 + threadIdx.x;
  if (idx >= NCH * ROWS * NHEADS) return;
  int z = idx / (ROWS * NHEADS);
  int rem = idx - z * (ROWS * NHEADS);
  int row = rem >> 3, head = rem & 7;
  bf16* kp = qkv + (long)z * ROWS * 384 + (long)row * 384 + 128 + head * 16;
  const float* w = kn + z * 8;
  #pragma unroll
  for (int hf = 0; hf < 2; hf++) {
    bf16x8 kv = *(bf16x8*)(kp + hf * 8);
    float f[8], s = 0.f;
    #pragma unroll
    for (int j = 0; j < 8; j++) { f[j] = (float)kv[j]; s += f[j] * f[j]; }
    float r = rsqrtf(s * 0.125f + EPS);
    bf16x8 o;
    #pragma unroll
    for (int j = 0; j < 8; j++) o[j] = (bf16)(f[j] * r * w[j]);
    *(bf16x8*)(kp + hf * 8) = o;
  }
}

// ---------------- MFMA causal differential attention, S^T formulation -------------
// V^T-only LDS (18.7 KB) -> 8 blocks/CU; grid (64,4,8) = 2048 blocks = exactly 8/CU,
// 32 waves/CU (cap). aK read from global 16B loads (K pre-normed by k_knorm, L2-hot
// via XCD grouping: same-slice blocks share linear_id%8). 16 workers/(slice,head):
// worker u gets pr=17-u, plus leftovers pr=1->u15, pr=0->u14; max load 18 chunks.
// S^T = K·Q^T; P^T feeds 16x16x16 PV from registers; Q rmsnorm in-register; exp2.
__global__ __launch_bounds__(256) void k_attn_mfma(
    const bf16* __restrict__ qkv, const float* __restrict__ lam,
    const float* __restrict__ hnw, const float* __restrict__ qn,
    bf16* __restrict__ dc) {
  __shared__ bf16 Vt[16 * 584];
  int tid = threadIdx.x;
  int slice = blockIdx.x; int zc = slice >> 3, b = slice & 7;
  int head = blockIdx.z;
  const bf16* qkvb = qkv + ((long)zc * ROWS + (long)b * Lq) * 384;
  for (int i = tid; i < 1152; i += 256) {
    int row = i >> 1, dh = i & 1;
    bf16x8 v = *(const bf16x8*)(qkvb + (long)row * 384 + 256 + head * 16 + dh * 8);
    #pragma unroll
    for (int j = 0; j < 8; j++) Vt[(dh * 8 + j) * 584 + row] = v[j];
  }
  __syncthreads();
  int wv = tid >> 6, lane = tid & 63;
  int lm = lane & 15, lq = lane >> 4;
  float lamv = lam[zc];
  float hwv[4];
  #pragma unroll
  for (int r = 0; r < 4; r++) hwv[r] = hnw[zc * 16 + lq * 4 + r] * (1.f - LAMINIT);
  float qw[8];
  #pragma unroll
  for (int j = 0; j < 8; j++) qw[j] = qn[zc * 8 + j];
  // 16 workers: u = blockIdx.y*4 + wv
  int u = blockIdx.y * 4 + wv;
  int prA = 17 - u;
  int prB = (u == 15) ? 1 : (u == 14) ? 0 : -1;
  for (int pi = 0; pi < 2; pi++) {
    int pr = pi ? prB : prA;
    if (pr < 0) continue;
    // Q B-frags (normed + pre-scaled by 1/sqrt(8)*log2e); bq0 on quad0, bq1 on quad1
    bf16x8 bq0[2] = {{}, {}}, bq1[2] = {{}, {}};
    if (lq < 2) {
      #pragma unroll
      for (int tile = 0; tile < 2; tile++) {
        bf16x8 t8 = *(const bf16x8*)(
            qkvb + (long)(pr * 32 + tile * 16 + lm) * 384 + head * 16 + lq * 8);
        float f[8], s = 0.f;
        #pragma unroll
        for (int j = 0; j < 8; j++) { f[j] = (float)t8[j]; s += f[j] * f[j]; }
        float r = rsqrtf(s * 0.125f + EPS) * QSCALE_E;
        bf16x8 n;
        #pragma unroll
        for (int j = 0; j < 8; j++) n[j] = (bf16)(f[j] * r * qw[j]);
        if (lq == 0) bq0[tile] = n; else bq1[tile] = n;
      }
    }
    f32x4 o[2][2] = {};
    float den[2][2] = {};
    for (int kc = 0; kc <= pr; kc++) {
      f32x4 sT[2][2][2] = {};   // [t][tile][half]; C-tile: col=q, row=k=lq*4+r
      #pragma unroll
      for (int t = 0; t < 2; t++) {
        bf16x8 aK = {};
        if (lq < 2) {
          int krow = kc * 32 + t * 16 + lm;
          aK = *(const bf16x8*)(qkvb + (long)krow * 384 + 128 + head * 16 + lq * 8);
        }
        #pragma unroll
        for (int tile = 0; tile < 2; tile++) {
          sT[t][tile][0] = __builtin_amdgcn_mfma_f32_16x16x32_bf16(aK, bq0[tile], sT[t][tile][0], 0, 0, 0);
          sT[t][tile][1] = __builtin_amdgcn_mfma_f32_16x16x32_bf16(aK, bq1[tile], sT[t][tile][1], 0, 0, 0);
        }
      }
      bool diag = (kc == pr);
      #pragma unroll
      for (int t = 0; t < 2; t++) {
        bf16x4 aV = *(const bf16x4*)(Vt + lm * 584 + kc * 32 + t * 16 + lq * 4);
        #pragma unroll
        for (int tile = 0; tile < 2; tile++) {
          if (diag && tile == 0 && t == 1) continue;      // fully masked sub-chunk
          bool masked = diag && (tile == t);              // triangular sub-chunk
          #pragma unroll
          for (int h2 = 0; h2 < 2; h2++) {
            bf16x4 pb;
            float dsum = 0.f;
            #pragma unroll
            for (int r = 0; r < 4; r++) {
              float ev = fexp2(sT[t][tile][h2][r]);
              if (masked && (lq * 4 + r > lm)) ev = 0.f;
              dsum += ev;
              pb[r] = (bf16)ev;
            }
            den[tile][h2] += dsum;
            o[tile][h2] = mfma16(aV, pb, o[tile][h2]);    // O^T += V^T · P^T
          }
        }
      }
    }
    #pragma unroll
    for (int tile = 0; tile < 2; tile++)
      #pragma unroll
      for (int h2 = 0; h2 < 2; h2++) {
        den[tile][h2] += __shfl_xor(den[tile][h2], 16);
        den[tile][h2] += __shfl_xor(den[tile][h2], 32);
      }
    #pragma unroll
    for (int tile = 0; tile < 2; tile++) {
      float inv1 = 1.f / den[tile][0];
      float inv2 = lamv / den[tile][1];
      float dff[4]; float ss = 0.f;
      #pragma unroll
      for (int r = 0; r < 4; r++) {
        dff[r] = o[tile][0][r] * inv1 - o[tile][1][r] * inv2;
        ss += dff[r] * dff[r];
      }
      ss += __shfl_xor(ss, 16);
      ss += __shfl_xor(ss, 32);
      float rr = rsqrtf(ss * 0.0625f + EPS);
      bf16x4 outp;
      #pragma unroll
      for (int r = 0; r < 4; r++) outp[r] = (bf16)(dff[r] * rr * hwv[r]);
      long rowg = (long)zc * ROWS + (long)b * Lq + pr * 32 + tile * 16 + lm;
      *(bf16x4*)(dc + rowg * 128 + head * 16 + lq * 4) = outp;
    }
  }
}

// ---------------- seg + pool fused: partials of (h_ch + rmsnorm(op))*rw ----------
__global__ __launch_bounds__(64) void k_segpool(const bf16* __restrict__ h,
    const bf16* __restrict__ op, const float* __restrict__ segw,
    const float* __restrict__ rw, float* __restrict__ part) {
  int lp = blockIdx.x, b = blockIdx.y, ch = blockIdx.z;
  int t = threadIdx.x;
  int c0 = t * 2;
  float w0 = segw[ch * 128 + c0], w1 = segw[ch * 128 + c0 + 1];
  float rwv = rw[b * 8 + ch];
  float a0 = 0.f, a1 = 0.f;
  for (int l = 0; l < 72; l++) {
    int row = b * Lq + lp * 72 + l;
    const bf16* oprow = op + (long)ch * ROWS * CW + (long)row * CW;
    bf16x2 yv = *(const bf16x2*)(oprow + c0);
    float y0 = (float)yv[0], y1 = (float)yv[1];
    float ss = y0 * y0 + y1 * y1;
    #pragma unroll
    for (int m = 1; m < 64; m <<= 1) ss += __shfl_xor(ss, m);
    float r = rsqrtf(ss * (1.f / 128.f) + EPS);
    bf16x2 hv = *(const bf16x2*)(h + (long)row * WIDTH + ch * 128 + c0);
    a0 += ((float)hv[0] + y0 * r * w0) * rwv;
    a1 += ((float)hv[1] + y1 * r * w1) * rwv;
  }
  float* dst = part + ((long)b * 8 + lp) * 1024 + ch * 128 + c0;
  dst[0] = a0; dst[1] = a1;
}

// ---------------- head (reads 8 pool partials): out = pooled @ hw + hb ------------
__global__ __launch_bounds__(256) void k_head(const float* __restrict__ part,
    const float* __restrict__ hw, const float* __restrict__ hb, float* __restrict__ out) {
  __shared__ float pool[1024];
  __shared__ float red[256];
  int b = blockIdx.x, t = threadIdx.x;
  for (int c = t; c < 1024; c += 256) {
    float a = 0.f;
    #pragma unroll
    for (int lp = 0; lp < 8; lp++) a += part[((long)b * 8 + lp) * 1024 + c];
    pool[c] = a * (1.f / 576.f);
  }
  __syncthreads();
  int j = t & 15, pt = t >> 4;
  float acc = 0.f;
  if (j < 10)
    for (int c = pt * 64; c < pt * 64 + 64; c++)
      acc += pool[c] * hw[c * 10 + j];
  red[t] = acc;
  __syncthreads();
  if (t < 10) {
    float a = hb[t];
    for (int p = 0; p < 16; p++) a += red[p * 16 + t];
    out[b * 10 + t] = a;
  }
}

// ---------------- launcher ----------------
extern "C" void kernel_launch(void* const* d_in, const int* in_sizes, int n_in,
                              void* d_out, int out_size, void* d_ws, size_t ws_size,
                              hipStream_t stream) {
  const float* x          = (const float*)d_in[0];
  const float* pixel_embed= (const float*)d_in[2];
  const float* freq_h     = (const float*)d_in[3];
  const float* freq_w     = (const float*)d_in[4];
  const float* phase_h    = (const float*)d_in[5];
  const float* phase_w    = (const float*)d_in[6];
  const float* pos_proj_w = (const float*)d_in[7];
  const float* pos_proj_b = (const float*)d_in[8];
  const float* embed_norm = (const float*)d_in[9];
  const float* se_w1      = (const float*)d_in[10];
  const float* se_b1      = (const float*)d_in[11];
  const float* se_w2      = (const float*)d_in[12];
  const float* se_b2      = (const float*)d_in[13];
  const float* mix_norm   = (const float*)d_in[14];
  const float* mlp_w1     = (const float*)d_in[15];
  const float* mlp_b1     = (const float*)d_in[16];
  const float* mlp_w2     = (const float*)d_in[17];
  const float* mlp_b2     = (const float*)d_in[18];
  const float* mlp_norm   = (const float*)d_in[19];
  const float* router_w   = (const float*)d_in[20];
  const float* router_b   = (const float*)d_in[21];
  const float* qkv_w      = (const float*)d_in[22];
  const float* qkv_b      = (const float*)d_in[23];
  const float* q_norm_w   = (const float*)d_in[24];
  const float* k_norm_w   = (const float*)d_in[25];
  const float* head_norm_w= (const float*)d_in[26];
  const float* lam_q1     = (const float*)d_in[27];
  const float* lam_k1     = (const float*)d_in[28];
  const float* lam_q2     = (const float*)d_in[29];
  const float* lam_k2     = (const float*)d_in[30];
  const float* out_w      = (const float*)d_in[31];
  const float* out_b      = (const float*)d_in[32];
  const float* seg_norm_w = (const float*)d_in[33];
  const float* head_w     = (const float*)d_in[34];
  const float* head_b     = (const float*)d_in[35];

  char* W = (char*)d_ws;
  bf16*  HB    = (bf16*)(W + B_HB);
  bf16*  G2B   = (bf16*)(W + B_G2B);
  bf16*  ENCB  = (bf16*)(W + B_ENCB);
  bf16*  POSWT = (bf16*)(W + B_POSWT);
  bf16*  QKVWT = (bf16*)(W + B_QKVWT);
  bf16*  OWT   = (bf16*)(W + B_OWT);
  float* SE    = (float*)(W + B_SE);
  float* T1    = (float*)(W + B_T1);
  float* MP    = (float*)(W + B_MP);
  float* RW    = (float*)(W + B_RW);
  float* LAM   = (float*)(W + B_LAM);
  char*  P     = W + B_POOL;
  float* POS   = (float*)P;
  bf16*  W1T   = (bf16*)P;
  bf16*  W2T   = (bf16*)(P + 8388608);
  bf16*  HID   = (bf16*)(P + 16777216);
  bf16*  QKV   = (bf16*)P;
  bf16*  DC    = (bf16*)(P + 28311552);
  float* out   = (float*)d_out;

  // 1. positional encoding -> bf16, weight cast, gemm -> POS (f32)
  k_enc_b<<<288, 256, 0, stream>>>(freq_h, freq_w, phase_h, phase_w, ENCB);
  k_tcast<<<dim3(32, 4, 1), 256, 0, stream>>>(pos_proj_w, POSWT, 128, 1024);
  gemm64<0, 0, 0><<<dim3(8, 10, 1), 256, 0, stream>>>(
      ENCB, 128, 0, POSWT, 128, 0, pos_proj_b, 0, POS, 1024, 0, 640, 1024, 128);
  // 2. embed + rmsnorm -> bf16 h
  k_embed<<<ROWS, 256, 0, stream>>>(x, pixel_embed, POS, embed_norm, HB);
  // 3. SE gate
  k_meanl_p<<<dim3(16, 8), 256, 0, stream>>>(HB, MP);
  k_se1<<<dim3(32, 8), 256, 0, stream>>>(MP, se_w1, se_b1, T1);
  k_se2<<<dim3(32, 8), 256, 0, stream>>>(T1, se_w2, se_b2, SE);
  k_mix_b<<<ROWS, 256, 0, stream>>>(HB, SE, mix_norm);
  // 4. MLP: split along hidden dim (2 halves of 2048), bf16 MFMA
  k_tcast<<<dim3(128, 32, 1), 256, 0, stream>>>(mlp_w1, W1T, 1024, 4096);
  k_tcast<<<dim3(32, 128, 1), 256, 0, stream>>>(mlp_w2, W2T, 4096, 1024);
  gemm_bt<1, 1><<<dim3(16, 36, 1), 256, 0, stream>>>(
      HB, 1024, 0, W1T, 0, mlp_b1, 0, HID, 2048, 0, 4608, 2048, 1024);
  gemm64<0, 1, 0><<<dim3(8, 72, 1), 256, 0, stream>>>(
      HID, 2048, 0, W2T, 4096, 0, mlp_b2, 0, G2B, 1024, 0, 4608, 1024, 2048);
  gemm_bt<1, 1><<<dim3(16, 36, 1), 256, 0, stream>>>(
      HB, 1024, 0, W1T + 2048L * 1024, 0, mlp_b1 + 2048, 0, HID, 2048, 0, 4608, 2048, 1024);
  gemm64<0, 1, 1><<<dim3(8, 72, 1), 256, 0, stream>>>(
      HID, 2048, 0, W2T + 2048, 4096, 0, nullptr, 0, G2B, 1024, 0, 4608, 1024, 2048);
  k_addnorm_b<<<ROWS, 256, 0, stream>>>(HB, G2B, mlp_norm);
  // 5. router + lambdas
  k_meanl_p<<<dim3(16, 8), 256, 0, stream>>>(HB, MP);
  k_router<<<8, 256, 0, stream>>>(MP, router_w, router_b,
                                  lam_q1, lam_k1, lam_q2, lam_k2, RW, LAM);
  // 6. channel weights cast
  k_tcast<<<dim3(12, 4, 8), 256, 0, stream>>>(qkv_w, QKVWT, 128, 384);
  k_tcast<<<dim3(4, 4, 8), 256, 0, stream>>>(out_w, OWT, 128, 128);
  // 7. all 8 channels: qkv-proj, K-norm in place, fused attention, out-proj in-place
  gemm64<1, 1, 0><<<dim3(3, 72, 8), 256, 0, stream>>>(
      HB, 1024, CW, QKVWT, 128, 384 * 128, qkv_b, 384,
      QKV, 384, (long)ROWS * 384, ROWS, 384, 128);
  k_knorm<<<1152, 256, 0, stream>>>(QKV, k_norm_w);
  k_attn_mfma<<<dim3(64, 4, 8), 256, 0, stream>>>(
      QKV, LAM, head_norm_w, q_norm_w, DC);
  gemm64<1, 1, 0><<<dim3(1, 72, 8), 256, 0, stream>>>(
      DC, 128, (long)ROWS * 128, OWT, 128, 128 * 128, out_b, 128,
      DC, 128, (long)ROWS * 128, ROWS, 128, 128);
  // 8. seg + pool fused -> partials; head folds the final reduce
  k_segpool<<<dim3(8, 8, 8), 64, 0, stream>>>(HB, DC, seg_norm_w, RW, MP);
  k_head<<<8, 256, 0, stream>>>(MP, head_w, head_b, out);
}

// Round 9
// 475.991 us; speedup vs baseline: 1.0574x; 1.0574x over previous
//
#include <hip/hip_runtime.h>
#include <math.h>

typedef __bf16 bf16;
typedef __bf16 bf16x8 __attribute__((ext_vector_type(8)));
typedef __bf16 bf16x4 __attribute__((ext_vector_type(4)));
typedef __bf16 bf16x2 __attribute__((ext_vector_type(2)));
typedef float f32x4 __attribute__((ext_vector_type(4)));
typedef short s16x4 __attribute__((ext_vector_type(4)));

// ---------------- constants ----------------
constexpr int Bsz = 8, HIMG = 24, WIMG = 24;
constexpr int Lq = 576;
constexpr int WIDTH = 1024, NCH = 8, CW = 128;
constexpr int NHEADS = 8, HD = 16, HALF = 8;
constexpr float EPS = 1e-6f;
constexpr float LAMINIT = 0.2f;
// 1/sqrt(8) * log2(e): scores exit MFMA in log2 domain -> v_exp_f32 directly
constexpr float QSCALE_E = 0.35355339059327373f * 1.4426950408889634f;
constexpr int ROWS = Bsz * Lq;              // 4608

__device__ __forceinline__ float fexp2(float x) {
#if __has_builtin(__builtin_amdgcn_exp2f)
  return __builtin_amdgcn_exp2f(x);
#else
  return exp2f(x);
#endif
}

// ---------------- workspace byte offsets ----------------
constexpr size_t B_HB    = 0;                        // bf16 h [4608][1024]
constexpr size_t B_G2B   = B_HB    + 9437184;        // bf16 g2 [4608][1024]; POS f32 early
constexpr size_t B_ENCB  = B_G2B   + 9437184;        // bf16 enc [640][128]
constexpr size_t B_POSWT = B_ENCB  + 163840;         // bf16 [1024][128]
constexpr size_t B_QKVWT = B_POSWT + 262144;         // bf16 [8][384][128]
constexpr size_t B_OWT   = B_QKVWT + 786432;         // bf16 [8][128][128]
constexpr size_t B_SE    = B_OWT   + 262144;         // f32 [8][1024]
constexpr size_t B_T1    = B_SE    + 32768;          // f32 [8][256]
constexpr size_t B_MP    = B_T1    + 8192;           // f32 [8][16][1024]
constexpr size_t B_RW    = B_MP    + 524288;         // f32 [64]
constexpr size_t B_LAM   = B_RW    + 256;            // f32 [8]
constexpr size_t B_POOL  = B_LAM   + 256;            // = 20914688; phase-shared pool
// pool (MLP small): W1T 8388608 | W2T 8388608 | HID 18874368        (58.7 MB total)
// pool (MLP big):   W1T 8388608 | W2T 8388608 | HID 37748736        (75.4 MB total)
// pool (chan):      QKV 28311552 | DC 9437184                        (58.7 MB total)
constexpr size_t WS_BIG = B_POOL + 8388608 + 8388608 + 37748736;     // 75440640

// ---------------- helpers ----------------
__device__ __forceinline__ float blockReduceSum256(float v, float* red) {
  #pragma unroll
  for (int off = 32; off; off >>= 1) v += __shfl_down(v, off, 64);
  int lane = threadIdx.x & 63, wid = threadIdx.x >> 6;
  if (lane == 0) red[wid] = v;
  __syncthreads();
  float total = 0.f;
  #pragma unroll
  for (int i = 0; i < 4; i++) total += red[i];
  return total;
}
__device__ __forceinline__ float silu(float x) { return x / (1.f + __expf(-x)); }

__device__ __forceinline__ void gl16(const bf16* g, bf16* l) {
  __builtin_amdgcn_global_load_lds(
      (const __attribute__((address_space(1))) void*)g,
      (__attribute__((address_space(3))) void*)l, 16, 0, 0);
}

// v_mfma_f32_16x16x16_bf16 wrapper (A,B = 4 bf16/lane; k = quad*4+j)
__device__ __forceinline__ f32x4 mfma16(bf16x4 a, bf16x4 b, f32x4 c) {
#if __has_builtin(__builtin_amdgcn_mfma_f32_16x16x16bf16_1k)
  union { bf16x4 h; s16x4 s; } ua, ub;
  ua.h = a; ub.h = b;
  return __builtin_amdgcn_mfma_f32_16x16x16bf16_1k(ua.s, ub.s, c, 0, 0, 0);
#else
  f32x4 d = c;
  asm volatile("v_mfma_f32_16x16x16_bf16 %0, %1, %2, %0"
               : "+v"(d) : "v"(a), "v"(b));
  return d;
#endif
}

// ---------------- batched cast+transpose of ALL weights, one dispatch -------------
// fp32 [K][N] -> bf16 [N][K]; block = one 32x32 tile.
__device__ __forceinline__ void tcast_tile(const float* __restrict__ W,
    bf16* __restrict__ Wt, int K, int N, long zo, int bx, int by) {
  __shared__ float t[32][33];
  int n0 = bx * 32, k0 = by * 32;
  int tid = threadIdx.x;
  int r = tid >> 3, c4 = (tid & 7) * 4;
  const float4 v = *(const float4*)(W + zo + (long)(k0 + r) * N + n0 + c4);
  t[c4 + 0][r] = v.x; t[c4 + 1][r] = v.y; t[c4 + 2][r] = v.z; t[c4 + 3][r] = v.w;
  __syncthreads();
  bf16* dst = Wt + zo + (long)(n0 + r) * K + k0 + c4;
  dst[0] = (bf16)t[r][c4 + 0]; dst[1] = (bf16)t[r][c4 + 1];
  dst[2] = (bf16)t[r][c4 + 2]; dst[3] = (bf16)t[r][c4 + 3];
}

__global__ __launch_bounds__(256) void k_tcast_all(
    const float* __restrict__ w1, const float* __restrict__ w2,
    const float* __restrict__ posw, const float* __restrict__ qkvw,
    const float* __restrict__ outw,
    bf16* __restrict__ W1T, bf16* __restrict__ W2T, bf16* __restrict__ POSWT,
    bf16* __restrict__ QKVWT, bf16* __restrict__ OWT) {
  int bid = blockIdx.x;
  if (bid < 4096) {                   // w1: 1024x4096, nx=128
    tcast_tile(w1, W1T, 1024, 4096, 0, bid % 128, bid / 128);
  } else if (bid < 8192) {            // w2: 4096x1024, nx=32
    int t = bid - 4096;
    tcast_tile(w2, W2T, 4096, 1024, 0, t % 32, t / 32);
  } else if (bid < 8320) {            // posw: 128x1024, nx=32
    int t = bid - 8192;
    tcast_tile(posw, POSWT, 128, 1024, 0, t % 32, t / 32);
  } else if (bid < 8704) {            // qkvw: 8 x (128x384), nx=12
    int t = bid - 8320;
    int z = t / 48; t -= z * 48;
    tcast_tile(qkvw, QKVWT, 128, 384, (long)z * 49152, t % 12, t / 12);
  } else {                            // outw: 8 x (128x128), nx=4
    int t = bid - 8704;
    int z = t / 16; t -= z * 16;
    tcast_tile(outw, OWT, 128, 128, (long)z * 16384, t % 4, t / 4);
  }
}

// ---------------- positional encoding (bf16 out) ----------------
__global__ void k_enc_b(const float* __restrict__ fh, const float* __restrict__ fw,
                        const float* __restrict__ ph, const float* __restrict__ pw,
                        bf16* __restrict__ enc) {
  int idx = blockIdx.x * blockDim.x + threadIdx.x;
  if (idx >= Lq * 128) return;
  int l = idx >> 7, c = idx & 127;
  int hh = l / WIMG, ww = l % WIMG;
  float v;
  if (c < 64) {
    int f = c & 31;
    float fr = log1pf(__expf(fh[f])) * 10.f;
    float a = (hh / (float)HIMG) * fr + ph[f];
    v = (c < 32) ? sinf(a) : cosf(a);
  } else {
    int f = c & 31;
    float fr = log1pf(__expf(fw[f])) * 10.f;
    float a = (ww / (float)WIMG) * fr + pw[f];
    v = (c < 96) ? sinf(a) : cosf(a);
  }
  enc[idx] = (bf16)v;
}

// ---------------- bf16 MFMA GEMM 128x128 ----------------
template <int ACT, int OUTBF>
__global__ __launch_bounds__(256) void gemm_bt(
    const bf16* __restrict__ A, int lda, long aZs,
    const bf16* __restrict__ Bt, long bZs,
    const float* __restrict__ bias, int biasZs,
    void* __restrict__ Cv, int ldc, long cZs,
    int M, int N, int K) {
  __shared__ bf16 As[128 * 32];
  __shared__ bf16 Bs[128 * 32];
  int tid = threadIdx.x;
  int m0 = blockIdx.y * 128, n0 = blockIdx.x * 128;
  int z = blockIdx.z;
  const bf16* Ab = A + (long)z * aZs;
  const bf16* Bb = Bt + (long)z * bZs;
  f32x4 acc[4][4] = {};
  int wv = tid >> 6, lane = tid & 63;
  int wrow = (wv >> 1) * 64, wcol = (wv & 1) * 64;
  int lm = lane & 15, lq = lane >> 4;
  const bf16* ag = Ab + (long)(m0 + (tid >> 2)) * lda + (tid & 3) * 8;
  const bf16* bg = Bb + (long)(n0 + (tid >> 2)) * K + (tid & 3) * 8;
  bf16* asd = As + tid * 8;
  bf16* bsd = Bs + tid * 8;
  for (int k0 = 0; k0 < K; k0 += 32) {
    gl16(ag + k0, asd);
    gl16(ag + k0 + 64L * lda, asd + 2048);
    gl16(bg + k0, bsd);
    gl16(bg + k0 + 64L * K, bsd + 2048);
    __syncthreads();
    bf16x8 af[4], bfr[4];
    #pragma unroll
    for (int i = 0; i < 4; i++) {
      af[i]  = *(const bf16x8*)(As + (wrow + i * 16 + lm) * 32 + lq * 8);
      bfr[i] = *(const bf16x8*)(Bs + (wcol + i * 16 + lm) * 32 + lq * 8);
    }
    #pragma unroll
    for (int i = 0; i < 4; i++)
      #pragma unroll
      for (int j = 0; j < 4; j++)
        acc[i][j] = __builtin_amdgcn_mfma_f32_16x16x32_bf16(af[i], bfr[j], acc[i][j], 0, 0, 0);
    __syncthreads();
  }
  long cz = (long)z * cZs;
  const float* bz = bias ? bias + (long)z * biasZs : nullptr;
  #pragma unroll
  for (int i = 0; i < 4; i++) {
    int row = m0 + wrow + i * 16 + lq * 4;
    #pragma unroll
    for (int j = 0; j < 4; j++) {
      int col = n0 + wcol + j * 16 + lm;
      float bv = bz ? bz[col] : 0.f;
      #pragma unroll
      for (int r = 0; r < 4; r++) {
        float v = acc[i][j][r] + bv;
        if (ACT == 1) v = silu(v);
        long off = cz + (long)(row + r) * ldc + col;
        if (OUTBF) ((bf16*)Cv)[off] = (bf16)v;
        else       ((float*)Cv)[off] = v;
      }
    }
  }
}

// ---------------- bf16 MFMA GEMM 64x128 tile ----------------
// NORM=1 (qkv mode): after silu, apply 8-col-group rmsnorm for Q (blockIdx.x==0,
// weight qn, prescale QSCALE_E) and K (x==1, weight kn); V (x==2) passthrough.
template <int ACT, int OUTBF, int ACC, int NORM>
__global__ __launch_bounds__(256) void gemm64(
    const bf16* __restrict__ A, int lda, long aZs,
    const bf16* __restrict__ Bt, int ldb, long bZs,
    const float* __restrict__ bias, int biasZs,
    void* __restrict__ Cv, int ldc, long cZs,
    int M, int N, int K,
    const float* __restrict__ qn, const float* __restrict__ kn) {
  __shared__ bf16 As[64 * 32];
  __shared__ bf16 Bs[128 * 32];
  int tid = threadIdx.x;
  int m0 = blockIdx.y * 64, n0 = blockIdx.x * 128;
  int z = blockIdx.z;
  const bf16* Ab = A + (long)z * aZs;
  const bf16* Bb = Bt + (long)z * bZs;
  f32x4 acc[4][2] = {};
  int wv = tid >> 6, lane = tid & 63;
  int lm = lane & 15, lq = lane >> 4;
  int wcol = wv * 32;
  const bf16* ag = Ab + (long)(m0 + (tid >> 2)) * lda + (tid & 3) * 8;
  const bf16* bg = Bb + (long)(n0 + (tid >> 2)) * ldb + (tid & 3) * 8;
  bf16* asd = As + tid * 8;
  bf16* bsd = Bs + tid * 8;
  for (int k0 = 0; k0 < K; k0 += 32) {
    gl16(ag + k0, asd);
    gl16(bg + k0, bsd);
    gl16(bg + k0 + 64L * ldb, bsd + 2048);
    __syncthreads();
    bf16x8 af[4], bfr[2];
    #pragma unroll
    for (int i = 0; i < 4; i++)
      af[i] = *(const bf16x8*)(As + (i * 16 + lm) * 32 + lq * 8);
    #pragma unroll
    for (int j = 0; j < 2; j++)
      bfr[j] = *(const bf16x8*)(Bs + (wcol + j * 16 + lm) * 32 + lq * 8);
    #pragma unroll
    for (int i = 0; i < 4; i++)
      #pragma unroll
      for (int j = 0; j < 2; j++)
        acc[i][j] = __builtin_amdgcn_mfma_f32_16x16x32_bf16(af[i], bfr[j], acc[i][j], 0, 0, 0);
    __syncthreads();
  }
  long cz = (long)z * cZs;
  const float* bz = bias ? bias + (long)z * biasZs : nullptr;
  if constexpr (NORM == 0) {
    #pragma unroll
    for (int i = 0; i < 4; i++) {
      int row = m0 + i * 16 + lq * 4;
      #pragma unroll
      for (int j = 0; j < 2; j++) {
        int col = n0 + wcol + j * 16 + lm;
        float bv = bz ? bz[col] : 0.f;
        #pragma unroll
        for (int r = 0; r < 4; r++) {
          float v = acc[i][j][r] + bv;
          long off = cz + (long)(row + r) * ldc + col;
          if (ACC) v += (float)((bf16*)Cv)[off];
          if (ACT == 1) v = silu(v);
          if (OUTBF) ((bf16*)Cv)[off] = (bf16)v;
          else       ((float*)Cv)[off] = v;
        }
      }
    }
  } else {
    int nsec = blockIdx.x;              // 0=Q, 1=K, 2=V
    bool don = nsec < 2;
    float wnv = 1.f;
    if (nsec == 0) wnv = qn[z * 8 + (lm & 7)] * QSCALE_E;
    else if (nsec == 1) wnv = kn[z * 8 + (lm & 7)];
    #pragma unroll
    for (int i = 0; i < 4; i++) {
      int row = m0 + i * 16 + lq * 4;
      #pragma unroll
      for (int j = 0; j < 2; j++) {
        int col = n0 + wcol + j * 16 + lm;
        float bv = bz ? bz[col] : 0.f;
        #pragma unroll
        for (int r = 0; r < 4; r++) {
          float v = acc[i][j][r] + bv;
          if (ACT == 1) v = silu(v);
          float s = v * v;
          s += __shfl_xor(s, 1);
          s += __shfl_xor(s, 2);
          s += __shfl_xor(s, 4);
          if (don) v = v * rsqrtf(s * 0.125f + EPS) * wnv;
          ((bf16*)Cv)[cz + (long)(row + r) * ldc + col] = (bf16)v;
        }
      }
    }
  }
}

// ---------------- embed + rmsnorm -> bf16 h ----------------
__global__ __launch_bounds__(256) void k_embed(const float* __restrict__ x,
    const float* __restrict__ emb, const float* __restrict__ pos,
    const float* __restrict__ nw, bf16* __restrict__ h) {
  __shared__ float red[4];
  int row = blockIdx.x;
  int l = row % Lq;
  int xi = (int)(x[row] * 255.f);
  xi = min(max(xi, 0), 255);
  const float* er = emb + (long)xi * WIDTH;
  const float* pr = pos + (long)l * WIDTH;
  int c0 = threadIdx.x * 4;
  float v[4]; float ss = 0.f;
  #pragma unroll
  for (int i = 0; i < 4; i++) { v[i] = er[c0 + i] + pr[c0 + i]; ss += v[i] * v[i]; }
  ss = blockReduceSum256(ss, red);
  float r = rsqrtf(ss / WIDTH + EPS);
  bf16* hr = h + (long)row * WIDTH;
  #pragma unroll
  for (int i = 0; i < 4; i++) hr[c0 + i] = (bf16)(v[i] * r * nw[c0 + i]);
}

// ---------------- mean over L, phase 1: 16 partials per b ----------------
__global__ void k_meanl_p(const bf16* __restrict__ h, float* __restrict__ part) {
  int lp = blockIdx.x, b = blockIdx.y, t = threadIdx.x;
  const bf16* p = h + ((long)b * Lq + (long)lp * 36) * WIDTH + t * 4;
  float a0 = 0, a1 = 0, a2 = 0, a3 = 0;
  for (int l = 0; l < 36; l++) {
    bf16x4 v = *(const bf16x4*)(p + (long)l * WIDTH);
    a0 += (float)v[0]; a1 += (float)v[1]; a2 += (float)v[2]; a3 += (float)v[3];
  }
  float* dst = part + ((long)b * 16 + lp) * WIDTH + t * 4;
  dst[0] = a0; dst[1] = a1; dst[2] = a2; dst[3] = a3;
}

// ---------------- SE phase 1 ----------------
__global__ __launch_bounds__(256) void k_se1(const float* __restrict__ part,
    const float* __restrict__ w1, const float* __restrict__ b1,
    float* __restrict__ t1) {
  __shared__ float sv[1024];
  __shared__ float red[256];
  int jb = blockIdx.x, b = blockIdx.y, t = threadIdx.x;
  for (int c = t; c < 1024; c += 256) {
    float a = 0.f;
    #pragma unroll
    for (int lp = 0; lp < 16; lp++) a += part[((long)b * 16 + lp) * 1024 + c];
    sv[c] = a * (1.f / 576.f);
  }
  __syncthreads();
  int j = t & 7, pt = t >> 3;
  int j0 = jb * 8;
  float acc = 0.f;
  int c0 = pt * 32;
  #pragma unroll 8
  for (int c = c0; c < c0 + 32; c++) acc += sv[c] * w1[c * 256 + j0 + j];
  red[t] = acc;
  __syncthreads();
  if (t < 8) {
    float a = b1[j0 + t];
    #pragma unroll
    for (int p = 0; p < 32; p++) a += red[p * 8 + t];
    t1[b * 256 + j0 + t] = silu(a);
  }
}

// ---------------- SE phase 2 ----------------
__global__ __launch_bounds__(256) void k_se2(const float* __restrict__ t1,
    const float* __restrict__ w2, const float* __restrict__ b2,
    float* __restrict__ s) {
  __shared__ float red[256];
  int jb = blockIdx.x, b = blockIdx.y, t = threadIdx.x;
  int j = t & 31, pt = t >> 5;
  int j0 = jb * 32;
  const float* tb = t1 + b * 256;
  float acc = 0.f;
  int c0 = pt * 32;
  #pragma unroll 8
  for (int c = c0; c < c0 + 32; c++) acc += tb[c] * w2[c * 1024 + j0 + j];
  red[t] = acc;
  __syncthreads();
  if (t < 32) {
    float a = b2[j0 + t];
    #pragma unroll
    for (int p = 0; p < 8; p++) a += red[p * 32 + t];
    s[b * 1024 + j0 + t] = 1.f / (1.f + __expf(-a));
  }
}

// ---------------- mix: h += rmsnorm(h*(s-1), mw) ----------------
__global__ __launch_bounds__(256) void k_mix_b(bf16* __restrict__ h,
    const float* __restrict__ s, const float* __restrict__ mw) {
  __shared__ float red[4];
  int row = blockIdx.x;
  int b = row / Lq;
  bf16* hr = h + (long)row * WIDTH;
  const float* sb = s + b * WIDTH;
  int c0 = threadIdx.x * 4;
  float hv[4], y[4]; float ss = 0.f;
  #pragma unroll
  for (int i = 0; i < 4; i++) {
    hv[i] = (float)hr[c0 + i];
    y[i] = hv[i] * (sb[c0 + i] - 1.f); ss += y[i] * y[i];
  }
  ss = blockReduceSum256(ss, red);
  float r = rsqrtf(ss / WIDTH + EPS);
  #pragma unroll
  for (int i = 0; i < 4; i++) hr[c0 + i] = (bf16)(hv[i] + y[i] * r * mw[c0 + i]);
}

// ---------------- h += rmsnorm(g, mw) ----------------
__global__ __launch_bounds__(256) void k_addnorm_b(bf16* __restrict__ h,
    const bf16* __restrict__ g, const float* __restrict__ mw) {
  __shared__ float red[4];
  int row = blockIdx.x;
  bf16* hr = h + (long)row * WIDTH;
  const bf16* gr = g + (long)row * WIDTH;
  int c0 = threadIdx.x * 4;
  float y[4]; float ss = 0.f;
  #pragma unroll
  for (int i = 0; i < 4; i++) { y[i] = (float)gr[c0 + i]; ss += y[i] * y[i]; }
  ss = blockReduceSum256(ss, red);
  float r = rsqrtf(ss / WIDTH + EPS);
  #pragma unroll
  for (int i = 0; i < 4; i++)
    hr[c0 + i] = (bf16)((float)hr[c0 + i] + y[i] * r * mw[c0 + i]);
}

// ---------------- router + lambdas ----------------
__global__ __launch_bounds__(256) void k_router(const float* __restrict__ part,
    const float* __restrict__ rwgt, const float* __restrict__ rb,
    const float* __restrict__ lq1, const float* __restrict__ lk1,
    const float* __restrict__ lq2, const float* __restrict__ lk2,
    float* __restrict__ rw, float* __restrict__ lam) {
  __shared__ float sv[1024];
  __shared__ float red[256];
  __shared__ float lg[8];
  int b = blockIdx.x, t = threadIdx.x;
  for (int c = t; c < 1024; c += 256) {
    float a = 0.f;
    #pragma unroll
    for (int lp = 0; lp < 16; lp++) a += part[((long)b * 16 + lp) * 1024 + c];
    sv[c] = a * (1.f / 576.f);
  }
  __syncthreads();
  int j = t & 7, pt = t >> 3;
  float acc = 0.f;
  int c0 = pt * 32;
  #pragma unroll 8
  for (int c = c0; c < c0 + 32; c++) acc += sv[c] * rwgt[c * 8 + j];
  red[t] = acc;
  __syncthreads();
  if (t < 8) {
    float a = rb[t];
    for (int p = 0; p < 32; p++) a += red[p * 8 + t];
    lg[t] = a;
  }
  __syncthreads();
  if (t == 0) {
    float v[8]; bool sel[8];
    #pragma unroll
    for (int i = 0; i < 8; i++) { v[i] = lg[i]; sel[i] = false; }
    int idxs[4]; float vals[4];
    for (int s = 0; s < 4; s++) {
      int bi = -1; float bv = -1e30f;
      for (int i = 0; i < 8; i++) if (!sel[i] && v[i] > bv) { bv = v[i]; bi = i; }
      sel[bi] = true; idxs[s] = bi; vals[s] = bv;
    }
    float m = vals[0], den = 0.f, e[4];
    for (int s = 0; s < 4; s++) { e[s] = __expf(vals[s] - m); den += e[s]; }
    for (int i = 0; i < 8; i++) rw[b * 8 + i] = 0.f;
    for (int s = 0; s < 4; s++) rw[b * 8 + idxs[s]] = e[s] / den;
  }
  if (b == 0 && t >= 8 && t < 16) {
    int c = t - 8;
    float d1 = 0.f, d2 = 0.f;
    for (int i = 0; i < 8; i++) {
      d1 += lq1[c * 8 + i] * lk1[c * 8 + i];
      d2 += lq2[c * 8 + i] * lk2[c * 8 + i];
    }
    lam[c] = __expf(d1) - __expf(d2) + LAMINIT;
  }
}

// ---------------- MFMA causal differential attention (R7 structure, prenormed) ----
// Q/K already rmsnormed (+silu, Q prescaled by 1/sqrt(8)*log2e) in qkv-gemm epilogue.
// grid (slice=64, y=2, head=8); Ks+Vt in LDS (37.1 KB, 4 blk/CU); balanced 8-worker
// schedule max 23 chunks; S^T = K·Q^T; P^T feeds 16x16x16 PV from registers.
__global__ __launch_bounds__(256) void k_attn_mfma(
    const bf16* __restrict__ qkv, const float* __restrict__ lam,
    const float* __restrict__ hnw, bf16* __restrict__ dc) {
  __shared__ bf16 Ks[576 * 16];
  __shared__ bf16 Vt[16 * 584];
  int tid = threadIdx.x;
  int slice = blockIdx.x; int zc = slice >> 3, b = slice & 7;
  int head = blockIdx.z;
  const bf16* qkvb = qkv + ((long)zc * ROWS + (long)b * Lq) * 384;
  for (int i = tid; i < 1152; i += 256) {
    int row = i >> 1, hf = i & 1;
    gl16(qkvb + (long)row * 384 + 128 + head * 16 + hf * 8, Ks + i * 8);
  }
  for (int i = tid; i < 1152; i += 256) {
    int row = i >> 1, dh = i & 1;
    bf16x8 v = *(const bf16x8*)(qkvb + (long)row * 384 + 256 + head * 16 + dh * 8);
    #pragma unroll
    for (int j = 0; j < 8; j++) Vt[(dh * 8 + j) * 584 + row] = v[j];
  }
  __syncthreads();
  int wv = tid >> 6, lane = tid & 63;
  int lm = lane & 15, lq = lane >> 4;
  float lamv = lam[zc];
  float hwv[4];
  #pragma unroll
  for (int r = 0; r < 4; r++) hwv[r] = hnw[zc * 16 + lq * 4 + r] * (1.f - LAMINIT);
  // balanced schedule: worker u = blockIdx.y*4 + wv (8 workers, max 23 chunks)
  int u = blockIdx.y * 4 + wv;
  int prA, prB, prC;
  if (u < 6) { prA = u + 2; prB = 17 - u; prC = -1; }
  else       { int v2 = u - 6; prA = v2; prB = 8 + v2; prC = 11 - v2; }
  for (int pi = 0; pi < 3; pi++) {
    int pr = (pi == 0) ? prA : (pi == 1) ? prB : prC;
    if (pr < 0) continue;
    // Q B-frags raw (already normed+scaled); bq0 on quad0, bq1 on quad1
    bf16x8 bq0[2] = {{}, {}}, bq1[2] = {{}, {}};
    if (lq < 2) {
      #pragma unroll
      for (int tile = 0; tile < 2; tile++) {
        bf16x8 t8 = *(const bf16x8*)(
            qkvb + (long)(pr * 32 + tile * 16 + lm) * 384 + head * 16 + lq * 8);
        if (lq == 0) bq0[tile] = t8; else bq1[tile] = t8;
      }
    }
    f32x4 o[2][2] = {};
    float den[2][2] = {};
    for (int kc = 0; kc <= pr; kc++) {
      f32x4 sT[2][2][2] = {};   // [t][tile][half]
      #pragma unroll
      for (int t = 0; t < 2; t++) {
        bf16x8 aK = {};
        if (lq < 2) aK = *(const bf16x8*)(Ks + (kc * 32 + t * 16 + lm) * 16 + lq * 8);
        #pragma unroll
        for (int tile = 0; tile < 2; tile++) {
          sT[t][tile][0] = __builtin_amdgcn_mfma_f32_16x16x32_bf16(aK, bq0[tile], sT[t][tile][0], 0, 0, 0);
          sT[t][tile][1] = __builtin_amdgcn_mfma_f32_16x16x32_bf16(aK, bq1[tile], sT[t][tile][1], 0, 0, 0);
        }
      }
      bool diag = (kc == pr);
      #pragma unroll
      for (int t = 0; t < 2; t++) {
        bf16x4 aV = *(const bf16x4*)(Vt + lm * 584 + kc * 32 + t * 16 + lq * 4);
        #pragma unroll
        for (int tile = 0; tile < 2; tile++) {
          if (diag && tile == 0 && t == 1) continue;
          bool masked = diag && (tile == t);
          #pragma unroll
          for (int h2 = 0; h2 < 2; h2++) {
            bf16x4 pb;
            float dsum = 0.f;
            #pragma unroll
            for (int r = 0; r < 4; r++) {
              float ev = fexp2(sT[t][tile][h2][r]);
              if (masked && (lq * 4 + r > lm)) ev = 0.f;
              dsum += ev;
              pb[r] = (bf16)ev;
            }
            den[tile][h2] += dsum;
            o[tile][h2] = mfma16(aV, pb, o[tile][h2]);
          }
        }
      }
    }
    #pragma unroll
    for (int tile = 0; tile < 2; tile++)
      #pragma unroll
      for (int h2 = 0; h2 < 2; h2++) {
        den[tile][h2] += __shfl_xor(den[tile][h2], 16);
        den[tile][h2] += __shfl_xor(den[tile][h2], 32);
      }
    #pragma unroll
    for (int tile = 0; tile < 2; tile++) {
      float inv1 = 1.f / den[tile][0];
      float inv2 = lamv / den[tile][1];
      float dff[4]; float ss = 0.f;
      #pragma unroll
      for (int r = 0; r < 4; r++) {
        dff[r] = o[tile][0][r] * inv1 - o[tile][1][r] * inv2;
        ss += dff[r] * dff[r];
      }
      ss += __shfl_xor(ss, 16);
      ss += __shfl_xor(ss, 32);
      float rr = rsqrtf(ss * 0.0625f + EPS);
      bf16x4 outp;
      #pragma unroll
      for (int r = 0; r < 4; r++) outp[r] = (bf16)(dff[r] * rr * hwv[r]);
      long rowg = (long)zc * ROWS + (long)b * Lq + pr * 32 + tile * 16 + lm;
      *(bf16x4*)(dc + rowg * 128 + head * 16 + lq * 4) = outp;
    }
  }
}

// ---------------- seg + pool fused: 16 bins, 1-wave blocks ----------------
__global__ __launch_bounds__(64) void k_segpool(const bf16* __restrict__ h,
    const bf16* __restrict__ op, const float* __restrict__ segw,
    const float* __restrict__ rw, float* __restrict__ part) {
  int lp = blockIdx.x, b = blockIdx.y, ch = blockIdx.z;
  int t = threadIdx.x;
  int c0 = t * 2;
  float w0 = segw[ch * 128 + c0], w1 = segw[ch * 128 + c0 + 1];
  float rwv = rw[b * 8 + ch];
  float a0 = 0.f, a1 = 0.f;
  for (int l = 0; l < 36; l++) {
    int row = b * Lq + lp * 36 + l;
    const bf16* oprow = op + (long)ch * ROWS * CW + (long)row * CW;
    bf16x2 yv = *(const bf16x2*)(oprow + c0);
    float y0 = (float)yv[0], y1 = (float)yv[1];
    float ss = y0 * y0 + y1 * y1;
    #pragma unroll
    for (int m = 1; m < 64; m <<= 1) ss += __shfl_xor(ss, m);
    float r = rsqrtf(ss * (1.f / 128.f) + EPS);
    bf16x2 hv = *(const bf16x2*)(h + (long)row * WIDTH + ch * 128 + c0);
    a0 += ((float)hv[0] + y0 * r * w0) * rwv;
    a1 += ((float)hv[1] + y1 * r * w1) * rwv;
  }
  float* dst = part + ((long)b * 16 + lp) * 1024 + ch * 128 + c0;
  dst[0] = a0; dst[1] = a1;
}

// ---------------- head (reads 16 pool partials) ----------------
__global__ __launch_bounds__(256) void k_head(const float* __restrict__ part,
    const float* __restrict__ hw, const float* __restrict__ hb, float* __restrict__ out) {
  __shared__ float pool[1024];
  __shared__ float red[256];
  int b = blockIdx.x, t = threadIdx.x;
  for (int c = t; c < 1024; c += 256) {
    float a = 0.f;
    #pragma unroll
    for (int lp = 0; lp < 16; lp++) a += part[((long)b * 16 + lp) * 1024 + c];
    pool[c] = a * (1.f / 576.f);
  }
  __syncthreads();
  int j = t & 15, pt = t >> 4;
  float acc = 0.f;
  if (j < 10)
    for (int c = pt * 64; c < pt * 64 + 64; c++)
      acc += pool[c] * hw[c * 10 + j];
  red[t] = acc;
  __syncthreads();
  if (t < 10) {
    float a = hb[t];
    for (int p = 0; p < 16; p++) a += red[p * 16 + t];
    out[b * 10 + t] = a;
  }
}

// ---------------- launcher ----------------
extern "C" void kernel_launch(void* const* d_in, const int* in_sizes, int n_in,
                              void* d_out, int out_size, void* d_ws, size_t ws_size,
                              hipStream_t stream) {
  const float* x          = (const float*)d_in[0];
  const float* pixel_embed= (const float*)d_in[2];
  const float* freq_h     = (const float*)d_in[3];
  const float* freq_w     = (const float*)d_in[4];
  const float* phase_h    = (const float*)d_in[5];
  const float* phase_w    = (const float*)d_in[6];
  const float* pos_proj_w = (const float*)d_in[7];
  const float* pos_proj_b = (const float*)d_in[8];
  const float* embed_norm = (const float*)d_in[9];
  const float* se_w1      = (const float*)d_in[10];
  const float* se_b1      = (const float*)d_in[11];
  const float* se_w2      = (const float*)d_in[12];
  const float* se_b2      = (const float*)d_in[13];
  const float* mix_norm   = (const float*)d_in[14];
  const float* mlp_w1     = (const float*)d_in[15];
  const float* mlp_b1     = (const float*)d_in[16];
  const float* mlp_w2     = (const float*)d_in[17];
  const float* mlp_b2     = (const float*)d_in[18];
  const float* mlp_norm   = (const float*)d_in[19];
  const float* router_w   = (const float*)d_in[20];
  const float* router_b   = (const float*)d_in[21];
  const float* qkv_w      = (const float*)d_in[22];
  const float* qkv_b      = (const float*)d_in[23];
  const float* q_norm_w   = (const float*)d_in[24];
  const float* k_norm_w   = (const float*)d_in[25];
  const float* head_norm_w= (const float*)d_in[26];
  const float* lam_q1     = (const float*)d_in[27];
  const float* lam_k1     = (const float*)d_in[28];
  const float* lam_q2     = (const float*)d_in[29];
  const float* lam_k2     = (const float*)d_in[30];
  const float* out_w      = (const float*)d_in[31];
  const float* out_b      = (const float*)d_in[32];
  const float* seg_norm_w = (const float*)d_in[33];
  const float* head_w     = (const float*)d_in[34];
  const float* head_b     = (const float*)d_in[35];

  char* W = (char*)d_ws;
  bf16*  HB    = (bf16*)(W + B_HB);
  bf16*  G2B   = (bf16*)(W + B_G2B);
  float* POS   = (float*)(W + B_G2B);      // POS lives in G2B region (dead until MLP)
  bf16*  ENCB  = (bf16*)(W + B_ENCB);
  bf16*  POSWT = (bf16*)(W + B_POSWT);
  bf16*  QKVWT = (bf16*)(W + B_QKVWT);
  bf16*  OWT   = (bf16*)(W + B_OWT);
  float* SE    = (float*)(W + B_SE);
  float* T1    = (float*)(W + B_T1);
  float* MP    = (float*)(W + B_MP);
  float* RW    = (float*)(W + B_RW);
  float* LAM   = (float*)(W + B_LAM);
  char*  P     = W + B_POOL;
  bf16*  W1T   = (bf16*)P;
  bf16*  W2T   = (bf16*)(P + 8388608);
  bf16*  HID   = (bf16*)(P + 16777216);
  bf16*  QKV   = (bf16*)P;
  bf16*  DC    = (bf16*)(P + 28311552);
  float* out   = (float*)d_out;
  const bool big = ws_size >= WS_BIG;

  // 0. all weight casts in one dispatch
  k_tcast_all<<<8832, 256, 0, stream>>>(mlp_w1, mlp_w2, pos_proj_w, qkv_w, out_w,
                                        W1T, W2T, POSWT, QKVWT, OWT);
  // 1. positional encoding + projection (POS f32 in G2B region)
  k_enc_b<<<288, 256, 0, stream>>>(freq_h, freq_w, phase_h, phase_w, ENCB);
  gemm64<0, 0, 0, 0><<<dim3(8, 10, 1), 256, 0, stream>>>(
      ENCB, 128, 0, POSWT, 128, 0, pos_proj_b, 0, POS, 1024, 0, 640, 1024, 128,
      nullptr, nullptr);
  // 2. embed + rmsnorm -> bf16 h
  k_embed<<<ROWS, 256, 0, stream>>>(x, pixel_embed, POS, embed_norm, HB);
  // 3. SE gate
  k_meanl_p<<<dim3(16, 8), 256, 0, stream>>>(HB, MP);
  k_se1<<<dim3(32, 8), 256, 0, stream>>>(MP, se_w1, se_b1, T1);
  k_se2<<<dim3(32, 8), 256, 0, stream>>>(T1, se_w2, se_b2, SE);
  k_mix_b<<<ROWS, 256, 0, stream>>>(HB, SE, mix_norm);
  // 4. MLP
  if (big) {
    // full-width HID: gemm1 one dispatch (z=2 N-halves), gemm2 one K=4096 dispatch
    gemm_bt<1, 1><<<dim3(16, 36, 2), 256, 0, stream>>>(
        HB, 1024, 0, W1T, 2048L * 1024, mlp_b1, 2048,
        HID, 4096, 2048, 4608, 2048, 1024);
    gemm64<0, 1, 0, 0><<<dim3(8, 72, 1), 256, 0, stream>>>(
        HID, 4096, 0, W2T, 4096, 0, mlp_b2, 0,
        G2B, 1024, 0, 4608, 1024, 4096, nullptr, nullptr);
  } else {
    gemm_bt<1, 1><<<dim3(16, 36, 1), 256, 0, stream>>>(
        HB, 1024, 0, W1T, 0, mlp_b1, 0, HID, 2048, 0, 4608, 2048, 1024);
    gemm64<0, 1, 0, 0><<<dim3(8, 72, 1), 256, 0, stream>>>(
        HID, 2048, 0, W2T, 4096, 0, mlp_b2, 0, G2B, 1024, 0, 4608, 1024, 2048,
        nullptr, nullptr);
    gemm_bt<1, 1><<<dim3(16, 36, 1), 256, 0, stream>>>(
        HB, 1024, 0, W1T + 2048L * 1024, 0, mlp_b1 + 2048, 0, HID, 2048, 0,
        4608, 2048, 1024);
    gemm64<0, 1, 1, 0><<<dim3(8, 72, 1), 256, 0, stream>>>(
        HID, 2048, 0, W2T + 2048, 4096, 0, nullptr, 0, G2B, 1024, 0,
        4608, 1024, 2048, nullptr, nullptr);
  }
  k_addnorm_b<<<ROWS, 256, 0, stream>>>(HB, G2B, mlp_norm);
  // 5. router + lambdas
  k_meanl_p<<<dim3(16, 8), 256, 0, stream>>>(HB, MP);
  k_router<<<8, 256, 0, stream>>>(MP, router_w, router_b,
                                  lam_q1, lam_k1, lam_q2, lam_k2, RW, LAM);
  // 6. qkv-proj with fused silu + Q/K rmsnorm (+ Q prescale) in epilogue
  gemm64<1, 1, 0, 1><<<dim3(3, 72, 8), 256, 0, stream>>>(
      HB, 1024, CW, QKVWT, 128, 384 * 128, qkv_b, 384,
      QKV, 384, (long)ROWS * 384, ROWS, 384, 128, q_norm_w, k_norm_w);
  // 7. attention (prenormed), out-proj in-place on DC
  k_attn_mfma<<<dim3(64, 2, 8), 256, 0, stream>>>(QKV, LAM, head_norm_w, DC);
  gemm64<1, 1, 0, 0><<<dim3(1, 72, 8), 256, 0, stream>>>(
      DC, 128, (long)ROWS * 128, OWT, 128, 128 * 128, out_b, 128,
      DC, 128, (long)ROWS * 128, ROWS, 128, 128, nullptr, nullptr);
  // 8. seg + pool fused -> 16 partials; head folds the final reduce
  k_segpool<<<dim3(16, 8, 8), 64, 0, stream>>>(HB, DC, seg_norm_w, RW, MP);
  k_head<<<8, 256, 0, stream>>>(MP, head_w, head_b, out);
}

// Round 10
// 452.475 us; speedup vs baseline: 1.1123x; 1.0520x over previous
//
#include <hip/hip_runtime.h>
#include <math.h>

typedef __bf16 bf16;
typedef __bf16 bf16x8 __attribute__((ext_vector_type(8)));
typedef __bf16 bf16x4 __attribute__((ext_vector_type(4)));
typedef __bf16 bf16x2 __attribute__((ext_vector_type(2)));
typedef float f32x4 __attribute__((ext_vector_type(4)));
typedef short s16x4 __attribute__((ext_vector_type(4)));

// ---------------- constants ----------------
constexpr int Bsz = 8, HIMG = 24, WIMG = 24;
constexpr int Lq = 576;
constexpr int WIDTH = 1024, NCH = 8, CW = 128;
constexpr int NHEADS = 8, HD = 16, HALF = 8;
constexpr float EPS = 1e-6f;
constexpr float LAMINIT = 0.2f;
// 1/sqrt(8) * log2(e): scores exit MFMA in log2 domain -> v_exp_f32 directly
constexpr float QSCALE_E = 0.35355339059327373f * 1.4426950408889634f;
constexpr int ROWS = Bsz * Lq;              // 4608

__device__ __forceinline__ float fexp2(float x) {
#if __has_builtin(__builtin_amdgcn_exp2f)
  return __builtin_amdgcn_exp2f(x);
#else
  return exp2f(x);
#endif
}

// ---------------- workspace byte offsets ----------------
constexpr size_t B_HB    = 0;                        // bf16 h [4608][1024]
constexpr size_t B_G2B   = B_HB    + 9437184;        // bf16 g2/partial0; POS f32 early
constexpr size_t B_ENCB  = B_G2B   + 9437184;        // bf16 enc [640][128]
constexpr size_t B_POSWT = B_ENCB  + 163840;         // bf16 [1024][128]
constexpr size_t B_QKVWT = B_POSWT + 262144;         // bf16 [8][384][128]
constexpr size_t B_OWT   = B_QKVWT + 786432;         // bf16 [8][128][128]
constexpr size_t B_SE    = B_OWT   + 262144;         // f32 [8][1024]
constexpr size_t B_T1    = B_SE    + 32768;          // f32 [8][256]
constexpr size_t B_MP    = B_T1    + 8192;           // f32 [8][16][1024]
constexpr size_t B_RW    = B_MP    + 524288;         // f32 [64]
constexpr size_t B_LAM   = B_RW    + 256;            // f32 [8]
constexpr size_t B_POOL  = B_LAM   + 256;            // = 20914688; phase-shared pool
// pool (MLP small): W1T 8388608 | W2T 8388608 | HID 18874368            (58.7 MB)
// pool (MLP big):   W1T 8388608 | W2T 8388608 | HID 37748736            (75.4 MB)
// pool (MLP big2):  ... + PART1 bf16 9437184 after HID                  (84.9 MB)
// pool (chan):      QKV 28311552 | DC 9437184 (out-proj IN-PLACE on DC) (58.7 MB)
constexpr size_t WS_BIG  = B_POOL + 8388608 + 8388608 + 37748736;     // 75440640
constexpr size_t WS_BIG2 = WS_BIG + 9437184;                          // 84877824

// ---------------- helpers ----------------
__device__ __forceinline__ float blockReduceSum256(float v, float* red) {
  #pragma unroll
  for (int off = 32; off; off >>= 1) v += __shfl_down(v, off, 64);
  int lane = threadIdx.x & 63, wid = threadIdx.x >> 6;
  if (lane == 0) red[wid] = v;
  __syncthreads();
  float total = 0.f;
  #pragma unroll
  for (int i = 0; i < 4; i++) total += red[i];
  return total;
}
__device__ __forceinline__ float silu(float x) { return x / (1.f + __expf(-x)); }

__device__ __forceinline__ void gl16(const bf16* g, bf16* l) {
  __builtin_amdgcn_global_load_lds(
      (const __attribute__((address_space(1))) void*)g,
      (__attribute__((address_space(3))) void*)l, 16, 0, 0);
}

// v_mfma_f32_16x16x16_bf16 wrapper (A,B = 4 bf16/lane; k = quad*4+j)
__device__ __forceinline__ f32x4 mfma16(bf16x4 a, bf16x4 b, f32x4 c) {
#if __has_builtin(__builtin_amdgcn_mfma_f32_16x16x16bf16_1k)
  union { bf16x4 h; s16x4 s; } ua, ub;
  ua.h = a; ub.h = b;
  return __builtin_amdgcn_mfma_f32_16x16x16bf16_1k(ua.s, ub.s, c, 0, 0, 0);
#else
  f32x4 d = c;
  asm volatile("v_mfma_f32_16x16x16_bf16 %0, %1, %2, %0"
               : "+v"(d) : "v"(a), "v"(b));
  return d;
#endif
}

// ---------------- batched cast+transpose of ALL weights, one dispatch -------------
__device__ __forceinline__ void tcast_tile(const float* __restrict__ W,
    bf16* __restrict__ Wt, int K, int N, long zo, int bx, int by) {
  __shared__ float t[32][33];
  int n0 = bx * 32, k0 = by * 32;
  int tid = threadIdx.x;
  int r = tid >> 3, c4 = (tid & 7) * 4;
  const float4 v = *(const float4*)(W + zo + (long)(k0 + r) * N + n0 + c4);
  t[c4 + 0][r] = v.x; t[c4 + 1][r] = v.y; t[c4 + 2][r] = v.z; t[c4 + 3][r] = v.w;
  __syncthreads();
  bf16* dst = Wt + zo + (long)(n0 + r) * K + k0 + c4;
  dst[0] = (bf16)t[r][c4 + 0]; dst[1] = (bf16)t[r][c4 + 1];
  dst[2] = (bf16)t[r][c4 + 2]; dst[3] = (bf16)t[r][c4 + 3];
}

__global__ __launch_bounds__(256) void k_tcast_all(
    const float* __restrict__ w1, const float* __restrict__ w2,
    const float* __restrict__ posw, const float* __restrict__ qkvw,
    const float* __restrict__ outw,
    bf16* __restrict__ W1T, bf16* __restrict__ W2T, bf16* __restrict__ POSWT,
    bf16* __restrict__ QKVWT, bf16* __restrict__ OWT) {
  int bid = blockIdx.x;
  if (bid < 4096) {
    tcast_tile(w1, W1T, 1024, 4096, 0, bid % 128, bid / 128);
  } else if (bid < 8192) {
    int t = bid - 4096;
    tcast_tile(w2, W2T, 4096, 1024, 0, t % 32, t / 32);
  } else if (bid < 8320) {
    int t = bid - 8192;
    tcast_tile(posw, POSWT, 128, 1024, 0, t % 32, t / 32);
  } else if (bid < 8704) {
    int t = bid - 8320;
    int z = t / 48; t -= z * 48;
    tcast_tile(qkvw, QKVWT, 128, 384, (long)z * 49152, t % 12, t / 12);
  } else {
    int t = bid - 8704;
    int z = t / 16; t -= z * 16;
    tcast_tile(outw, OWT, 128, 128, (long)z * 16384, t % 4, t / 4);
  }
}

// ---------------- positional encoding (bf16 out) ----------------
__global__ void k_enc_b(const float* __restrict__ fh, const float* __restrict__ fw,
                        const float* __restrict__ ph, const float* __restrict__ pw,
                        bf16* __restrict__ enc) {
  int idx = blockIdx.x * blockDim.x + threadIdx.x;
  if (idx >= Lq * 128) return;
  int l = idx >> 7, c = idx & 127;
  int hh = l / WIMG, ww = l % WIMG;
  float v;
  if (c < 64) {
    int f = c & 31;
    float fr = log1pf(__expf(fh[f])) * 10.f;
    float a = (hh / (float)HIMG) * fr + ph[f];
    v = (c < 32) ? sinf(a) : cosf(a);
  } else {
    int f = c & 31;
    float fr = log1pf(__expf(fw[f])) * 10.f;
    float a = (ww / (float)WIMG) * fr + pw[f];
    v = (c < 96) ? sinf(a) : cosf(a);
  }
  enc[idx] = (bf16)v;
}

// ---------------- bf16 MFMA GEMM 128x128 (with ldb for K-split B panels) ----------
template <int ACT, int OUTBF>
__global__ __launch_bounds__(256) void gemm_bt(
    const bf16* __restrict__ A, int lda, long aZs,
    const bf16* __restrict__ Bt, int ldb, long bZs,
    const float* __restrict__ bias, int biasZs,
    void* __restrict__ Cv, int ldc, long cZs,
    int M, int N, int K) {
  __shared__ bf16 As[128 * 32];
  __shared__ bf16 Bs[128 * 32];
  int tid = threadIdx.x;
  int m0 = blockIdx.y * 128, n0 = blockIdx.x * 128;
  int z = blockIdx.z;
  const bf16* Ab = A + (long)z * aZs;
  const bf16* Bb = Bt + (long)z * bZs;
  f32x4 acc[4][4] = {};
  int wv = tid >> 6, lane = tid & 63;
  int wrow = (wv >> 1) * 64, wcol = (wv & 1) * 64;
  int lm = lane & 15, lq = lane >> 4;
  const bf16* ag = Ab + (long)(m0 + (tid >> 2)) * lda + (tid & 3) * 8;
  const bf16* bg = Bb + (long)(n0 + (tid >> 2)) * ldb + (tid & 3) * 8;
  bf16* asd = As + tid * 8;
  bf16* bsd = Bs + tid * 8;
  for (int k0 = 0; k0 < K; k0 += 32) {
    gl16(ag + k0, asd);
    gl16(ag + k0 + 64L * lda, asd + 2048);
    gl16(bg + k0, bsd);
    gl16(bg + k0 + 64L * ldb, bsd + 2048);
    __syncthreads();
    bf16x8 af[4], bfr[4];
    #pragma unroll
    for (int i = 0; i < 4; i++) {
      af[i]  = *(const bf16x8*)(As + (wrow + i * 16 + lm) * 32 + lq * 8);
      bfr[i] = *(const bf16x8*)(Bs + (wcol + i * 16 + lm) * 32 + lq * 8);
    }
    #pragma unroll
    for (int i = 0; i < 4; i++)
      #pragma unroll
      for (int j = 0; j < 4; j++)
        acc[i][j] = __builtin_amdgcn_mfma_f32_16x16x32_bf16(af[i], bfr[j], acc[i][j], 0, 0, 0);
    __syncthreads();
  }
  long cz = (long)z * cZs;
  const float* bz = bias ? bias + (long)z * biasZs : nullptr;
  #pragma unroll
  for (int i = 0; i < 4; i++) {
    int row = m0 + wrow + i * 16 + lq * 4;
    #pragma unroll
    for (int j = 0; j < 4; j++) {
      int col = n0 + wcol + j * 16 + lm;
      float bv = bz ? bz[col] : 0.f;
      #pragma unroll
      for (int r = 0; r < 4; r++) {
        float v = acc[i][j][r] + bv;
        if (ACT == 1) v = silu(v);
        long off = cz + (long)(row + r) * ldc + col;
        if (OUTBF) ((bf16*)Cv)[off] = (bf16)v;
        else       ((float*)Cv)[off] = v;
      }
    }
  }
}

// ---------------- bf16 MFMA GEMM 64x128 tile ----------------
// NORM=1 (qkv mode): after silu, 8-col-group rmsnorm for Q (x==0, qn, prescale) and
// K (x==1, kn); V (x==2) passthrough.
template <int ACT, int OUTBF, int ACC, int NORM>
__global__ __launch_bounds__(256) void gemm64(
    const bf16* __restrict__ A, int lda, long aZs,
    const bf16* __restrict__ Bt, int ldb, long bZs,
    const float* __restrict__ bias, int biasZs,
    void* __restrict__ Cv, int ldc, long cZs,
    int M, int N, int K,
    const float* __restrict__ qn, const float* __restrict__ kn) {
  __shared__ bf16 As[64 * 32];
  __shared__ bf16 Bs[128 * 32];
  int tid = threadIdx.x;
  int m0 = blockIdx.y * 64, n0 = blockIdx.x * 128;
  int z = blockIdx.z;
  const bf16* Ab = A + (long)z * aZs;
  const bf16* Bb = Bt + (long)z * bZs;
  f32x4 acc[4][2] = {};
  int wv = tid >> 6, lane = tid & 63;
  int lm = lane & 15, lq = lane >> 4;
  int wcol = wv * 32;
  const bf16* ag = Ab + (long)(m0 + (tid >> 2)) * lda + (tid & 3) * 8;
  const bf16* bg = Bb + (long)(n0 + (tid >> 2)) * ldb + (tid & 3) * 8;
  bf16* asd = As + tid * 8;
  bf16* bsd = Bs + tid * 8;
  for (int k0 = 0; k0 < K; k0 += 32) {
    gl16(ag + k0, asd);
    gl16(bg + k0, bsd);
    gl16(bg + k0 + 64L * ldb, bsd + 2048);
    __syncthreads();
    bf16x8 af[4], bfr[2];
    #pragma unroll
    for (int i = 0; i < 4; i++)
      af[i] = *(const bf16x8*)(As + (i * 16 + lm) * 32 + lq * 8);
    #pragma unroll
    for (int j = 0; j < 2; j++)
      bfr[j] = *(const bf16x8*)(Bs + (wcol + j * 16 + lm) * 32 + lq * 8);
    #pragma unroll
    for (int i = 0; i < 4; i++)
      #pragma unroll
      for (int j = 0; j < 2; j++)
        acc[i][j] = __builtin_amdgcn_mfma_f32_16x16x32_bf16(af[i], bfr[j], acc[i][j], 0, 0, 0);
    __syncthreads();
  }
  long cz = (long)z * cZs;
  const float* bz = bias ? bias + (long)z * biasZs : nullptr;
  if constexpr (NORM == 0) {
    #pragma unroll
    for (int i = 0; i < 4; i++) {
      int row = m0 + i * 16 + lq * 4;
      #pragma unroll
      for (int j = 0; j < 2; j++) {
        int col = n0 + wcol + j * 16 + lm;
        float bv = bz ? bz[col] : 0.f;
        #pragma unroll
        for (int r = 0; r < 4; r++) {
          float v = acc[i][j][r] + bv;
          long off = cz + (long)(row + r) * ldc + col;
          if (ACC) v += (float)((bf16*)Cv)[off];
          if (ACT == 1) v = silu(v);
          if (OUTBF) ((bf16*)Cv)[off] = (bf16)v;
          else       ((float*)Cv)[off] = v;
        }
      }
    }
  } else {
    int nsec = blockIdx.x;              // 0=Q, 1=K, 2=V
    bool don = nsec < 2;
    float wnv = 1.f;
    if (nsec == 0) wnv = qn[z * 8 + (lm & 7)] * QSCALE_E;
    else if (nsec == 1) wnv = kn[z * 8 + (lm & 7)];
    #pragma unroll
    for (int i = 0; i < 4; i++) {
      int row = m0 + i * 16 + lq * 4;
      #pragma unroll
      for (int j = 0; j < 2; j++) {
        int col = n0 + wcol + j * 16 + lm;
        float bv = bz ? bz[col] : 0.f;
        #pragma unroll
        for (int r = 0; r < 4; r++) {
          float v = acc[i][j][r] + bv;
          if (ACT == 1) v = silu(v);
          float s = v * v;
          s += __shfl_xor(s, 1);
          s += __shfl_xor(s, 2);
          s += __shfl_xor(s, 4);
          if (don) v = v * rsqrtf(s * 0.125f + EPS) * wnv;
          ((bf16*)Cv)[cz + (long)(row + r) * ldc + col] = (bf16)v;
        }
      }
    }
  }
}

// ---------------- embed + rmsnorm -> bf16 h ----------------
__global__ __launch_bounds__(256) void k_embed(const float* __restrict__ x,
    const float* __restrict__ emb, const float* __restrict__ pos,
    const float* __restrict__ nw, bf16* __restrict__ h) {
  __shared__ float red[4];
  int row = blockIdx.x;
  int l = row % Lq;
  int xi = (int)(x[row] * 255.f);
  xi = min(max(xi, 0), 255);
  const float* er = emb + (long)xi * WIDTH;
  const float* pr = pos + (long)l * WIDTH;
  int c0 = threadIdx.x * 4;
  float v[4]; float ss = 0.f;
  #pragma unroll
  for (int i = 0; i < 4; i++) { v[i] = er[c0 + i] + pr[c0 + i]; ss += v[i] * v[i]; }
  ss = blockReduceSum256(ss, red);
  float r = rsqrtf(ss / WIDTH + EPS);
  bf16* hr = h + (long)row * WIDTH;
  #pragma unroll
  for (int i = 0; i < 4; i++) hr[c0 + i] = (bf16)(v[i] * r * nw[c0 + i]);
}

// ---------------- mean over L, phase 1: 16 partials per b ----------------
__global__ void k_meanl_p(const bf16* __restrict__ h, float* __restrict__ part) {
  int lp = blockIdx.x, b = blockIdx.y, t = threadIdx.x;
  const bf16* p = h + ((long)b * Lq + (long)lp * 36) * WIDTH + t * 4;
  float a0 = 0, a1 = 0, a2 = 0, a3 = 0;
  for (int l = 0; l < 36; l++) {
    bf16x4 v = *(const bf16x4*)(p + (long)l * WIDTH);
    a0 += (float)v[0]; a1 += (float)v[1]; a2 += (float)v[2]; a3 += (float)v[3];
  }
  float* dst = part + ((long)b * 16 + lp) * WIDTH + t * 4;
  dst[0] = a0; dst[1] = a1; dst[2] = a2; dst[3] = a3;
}

// ---------------- SE phase 1 ----------------
__global__ __launch_bounds__(256) void k_se1(const float* __restrict__ part,
    const float* __restrict__ w1, const float* __restrict__ b1,
    float* __restrict__ t1) {
  __shared__ float sv[1024];
  __shared__ float red[256];
  int jb = blockIdx.x, b = blockIdx.y, t = threadIdx.x;
  for (int c = t; c < 1024; c += 256) {
    float a = 0.f;
    #pragma unroll
    for (int lp = 0; lp < 16; lp++) a += part[((long)b * 16 + lp) * 1024 + c];
    sv[c] = a * (1.f / 576.f);
  }
  __syncthreads();
  int j = t & 7, pt = t >> 3;
  int j0 = jb * 8;
  float acc = 0.f;
  int c0 = pt * 32;
  #pragma unroll 8
  for (int c = c0; c < c0 + 32; c++) acc += sv[c] * w1[c * 256 + j0 + j];
  red[t] = acc;
  __syncthreads();
  if (t < 8) {
    float a = b1[j0 + t];
    #pragma unroll
    for (int p = 0; p < 32; p++) a += red[p * 8 + t];
    t1[b * 256 + j0 + t] = silu(a);
  }
}

// ---------------- SE phase 2 ----------------
__global__ __launch_bounds__(256) void k_se2(const float* __restrict__ t1,
    const float* __restrict__ w2, const float* __restrict__ b2,
    float* __restrict__ s) {
  __shared__ float red[256];
  int jb = blockIdx.x, b = blockIdx.y, t = threadIdx.x;
  int j = t & 31, pt = t >> 5;
  int j0 = jb * 32;
  const float* tb = t1 + b * 256;
  float acc = 0.f;
  int c0 = pt * 32;
  #pragma unroll 8
  for (int c = c0; c < c0 + 32; c++) acc += tb[c] * w2[c * 1024 + j0 + j];
  red[t] = acc;
  __syncthreads();
  if (t < 32) {
    float a = b2[j0 + t];
    #pragma unroll
    for (int p = 0; p < 8; p++) a += red[p * 32 + t];
    s[b * 1024 + j0 + t] = 1.f / (1.f + __expf(-a));
  }
}

// ---------------- mix: h += rmsnorm(h*(s-1), mw) ----------------
__global__ __launch_bounds__(256) void k_mix_b(bf16* __restrict__ h,
    const float* __restrict__ s, const float* __restrict__ mw) {
  __shared__ float red[4];
  int row = blockIdx.x;
  int b = row / Lq;
  bf16* hr = h + (long)row * WIDTH;
  const float* sb = s + b * WIDTH;
  int c0 = threadIdx.x * 4;
  float hv[4], y[4]; float ss = 0.f;
  #pragma unroll
  for (int i = 0; i < 4; i++) {
    hv[i] = (float)hr[c0 + i];
    y[i] = hv[i] * (sb[c0 + i] - 1.f); ss += y[i] * y[i];
  }
  ss = blockReduceSum256(ss, red);
  float r = rsqrtf(ss / WIDTH + EPS);
  #pragma unroll
  for (int i = 0; i < 4; i++) hr[c0 + i] = (bf16)(hv[i] + y[i] * r * mw[c0 + i]);
}

// ---------------- h += rmsnorm(g, mw) ----------------
__global__ __launch_bounds__(256) void k_addnorm_b(bf16* __restrict__ h,
    const bf16* __restrict__ g, const float* __restrict__ mw) {
  __shared__ float red[4];
  int row = blockIdx.x;
  bf16* hr = h + (long)row * WIDTH;
  const bf16* gr = g + (long)row * WIDTH;
  int c0 = threadIdx.x * 4;
  float y[4]; float ss = 0.f;
  #pragma unroll
  for (int i = 0; i < 4; i++) { y[i] = (float)gr[c0 + i]; ss += y[i] * y[i]; }
  ss = blockReduceSum256(ss, red);
  float r = rsqrtf(ss / WIDTH + EPS);
  #pragma unroll
  for (int i = 0; i < 4; i++)
    hr[c0 + i] = (bf16)((float)hr[c0 + i] + y[i] * r * mw[c0 + i]);
}

// ---------------- h += rmsnorm(p0 + p1 + b2, mw)  (K-split MLP partials) ----------
__global__ __launch_bounds__(256) void k_addnorm2(bf16* __restrict__ h,
    const bf16* __restrict__ p0, const bf16* __restrict__ p1,
    const float* __restrict__ b2, const float* __restrict__ mw) {
  __shared__ float red[4];
  int row = blockIdx.x;
  bf16* hr = h + (long)row * WIDTH;
  const bf16* g0 = p0 + (long)row * WIDTH;
  const bf16* g1 = p1 + (long)row * WIDTH;
  int c0 = threadIdx.x * 4;
  float y[4]; float ss = 0.f;
  #pragma unroll
  for (int i = 0; i < 4; i++) {
    y[i] = (float)g0[c0 + i] + (float)g1[c0 + i] + b2[c0 + i];
    ss += y[i] * y[i];
  }
  ss = blockReduceSum256(ss, red);
  float r = rsqrtf(ss / WIDTH + EPS);
  #pragma unroll
  for (int i = 0; i < 4; i++)
    hr[c0 + i] = (bf16)((float)hr[c0 + i] + y[i] * r * mw[c0 + i]);
}

// ---------------- router + lambdas ----------------
__global__ __launch_bounds__(256) void k_router(const float* __restrict__ part,
    const float* __restrict__ rwgt, const float* __restrict__ rb,
    const float* __restrict__ lq1, const float* __restrict__ lk1,
    const float* __restrict__ lq2, const float* __restrict__ lk2,
    float* __restrict__ rw, float* __restrict__ lam) {
  __shared__ float sv[1024];
  __shared__ float red[256];
  __shared__ float lg[8];
  int b = blockIdx.x, t = threadIdx.x;
  for (int c = t; c < 1024; c += 256) {
    float a = 0.f;
    #pragma unroll
    for (int lp = 0; lp < 16; lp++) a += part[((long)b * 16 + lp) * 1024 + c];
    sv[c] = a * (1.f / 576.f);
  }
  __syncthreads();
  int j = t & 7, pt = t >> 3;
  float acc = 0.f;
  int c0 = pt * 32;
  #pragma unroll 8
  for (int c = c0; c < c0 + 32; c++) acc += sv[c] * rwgt[c * 8 + j];
  red[t] = acc;
  __syncthreads();
  if (t < 8) {
    float a = rb[t];
    for (int p = 0; p < 32; p++) a += red[p * 8 + t];
    lg[t] = a;
  }
  __syncthreads();
  if (t == 0) {
    float v[8]; bool sel[8];
    #pragma unroll
    for (int i = 0; i < 8; i++) { v[i] = lg[i]; sel[i] = false; }
    int idxs[4]; float vals[4];
    for (int s = 0; s < 4; s++) {
      int bi = -1; float bv = -1e30f;
      for (int i = 0; i < 8; i++) if (!sel[i] && v[i] > bv) { bv = v[i]; bi = i; }
      sel[bi] = true; idxs[s] = bi; vals[s] = bv;
    }
    float m = vals[0], den = 0.f, e[4];
    for (int s = 0; s < 4; s++) { e[s] = __expf(vals[s] - m); den += e[s]; }
    for (int i = 0; i < 8; i++) rw[b * 8 + i] = 0.f;
    for (int s = 0; s < 4; s++) rw[b * 8 + idxs[s]] = e[s] / den;
  }
  if (b == 0 && t >= 8 && t < 16) {
    int c = t - 8;
    float d1 = 0.f, d2 = 0.f;
    for (int i = 0; i < 8; i++) {
      d1 += lq1[c * 8 + i] * lk1[c * 8 + i];
      d2 += lq2[c * 8 + i] * lk2[c * 8 + i];
    }
    lam[c] = __expf(d1) - __expf(d2) + LAMINIT;
  }
}

// ---------------- MFMA causal differential attention (prenormed Q/K) --------------
__global__ __launch_bounds__(256) void k_attn_mfma(
    const bf16* __restrict__ qkv, const float* __restrict__ lam,
    const float* __restrict__ hnw, bf16* __restrict__ dc) {
  __shared__ bf16 Ks[576 * 16];
  __shared__ bf16 Vt[16 * 584];
  int tid = threadIdx.x;
  int slice = blockIdx.x; int zc = slice >> 3, b = slice & 7;
  int head = blockIdx.z;
  const bf16* qkvb = qkv + ((long)zc * ROWS + (long)b * Lq) * 384;
  for (int i = tid; i < 1152; i += 256) {
    int row = i >> 1, hf = i & 1;
    gl16(qkvb + (long)row * 384 + 128 + head * 16 + hf * 8, Ks + i * 8);
  }
  for (int i = tid; i < 1152; i += 256) {
    int row = i >> 1, dh = i & 1;
    bf16x8 v = *(const bf16x8*)(qkvb + (long)row * 384 + 256 + head * 16 + dh * 8);
    #pragma unroll
    for (int j = 0; j < 8; j++) Vt[(dh * 8 + j) * 584 + row] = v[j];
  }
  __syncthreads();
  int wv = tid >> 6, lane = tid & 63;
  int lm = lane & 15, lq = lane >> 4;
  float lamv = lam[zc];
  float hwv[4];
  #pragma unroll
  for (int r = 0; r < 4; r++) hwv[r] = hnw[zc * 16 + lq * 4 + r] * (1.f - LAMINIT);
  int u = blockIdx.y * 4 + wv;
  int prA, prB, prC;
  if (u < 6) { prA = u + 2; prB = 17 - u; prC = -1; }
  else       { int v2 = u - 6; prA = v2; prB = 8 + v2; prC = 11 - v2; }
  for (int pi = 0; pi < 3; pi++) {
    int pr = (pi == 0) ? prA : (pi == 1) ? prB : prC;
    if (pr < 0) continue;
    bf16x8 bq0[2] = {{}, {}}, bq1[2] = {{}, {}};
    if (lq < 2) {
      #pragma unroll
      for (int tile = 0; tile < 2; tile++) {
        bf16x8 t8 = *(const bf16x8*)(
            qkvb + (long)(pr * 32 + tile * 16 + lm) * 384 + head * 16 + lq * 8);
        if (lq == 0) bq0[tile] = t8; else bq1[tile] = t8;
      }
    }
    f32x4 o[2][2] = {};
    float den[2][2] = {};
    for (int kc = 0; kc <= pr; kc++) {
      f32x4 sT[2][2][2] = {};
      #pragma unroll
      for (int t = 0; t < 2; t++) {
        bf16x8 aK = {};
        if (lq < 2) aK = *(const bf16x8*)(Ks + (kc * 32 + t * 16 + lm) * 16 + lq * 8);
        #pragma unroll
        for (int tile = 0; tile < 2; tile++) {
          sT[t][tile][0] = __builtin_amdgcn_mfma_f32_16x16x32_bf16(aK, bq0[tile], sT[t][tile][0], 0, 0, 0);
          sT[t][tile][1] = __builtin_amdgcn_mfma_f32_16x16x32_bf16(aK, bq1[tile], sT[t][tile][1], 0, 0, 0);
        }
      }
      bool diag = (kc == pr);
      #pragma unroll
      for (int t = 0; t < 2; t++) {
        bf16x4 aV = *(const bf16x4*)(Vt + lm * 584 + kc * 32 + t * 16 + lq * 4);
        #pragma unroll
        for (int tile = 0; tile < 2; tile++) {
          if (diag && tile == 0 && t == 1) continue;
          bool masked = diag && (tile == t);
          #pragma unroll
          for (int h2 = 0; h2 < 2; h2++) {
            bf16x4 pb;
            float dsum = 0.f;
            #pragma unroll
            for (int r = 0; r < 4; r++) {
              float ev = fexp2(sT[t][tile][h2][r]);
              if (masked && (lq * 4 + r > lm)) ev = 0.f;
              dsum += ev;
              pb[r] = (bf16)ev;
            }
            den[tile][h2] += dsum;
            o[tile][h2] = mfma16(aV, pb, o[tile][h2]);
          }
        }
      }
    }
    #pragma unroll
    for (int tile = 0; tile < 2; tile++)
      #pragma unroll
      for (int h2 = 0; h2 < 2; h2++) {
        den[tile][h2] += __shfl_xor(den[tile][h2], 16);
        den[tile][h2] += __shfl_xor(den[tile][h2], 32);
      }
    #pragma unroll
    for (int tile = 0; tile < 2; tile++) {
      float inv1 = 1.f / den[tile][0];
      float inv2 = lamv / den[tile][1];
      float dff[4]; float ss = 0.f;
      #pragma unroll
      for (int r = 0; r < 4; r++) {
        dff[r] = o[tile][0][r] * inv1 - o[tile][1][r] * inv2;
        ss += dff[r] * dff[r];
      }
      ss += __shfl_xor(ss, 16);
      ss += __shfl_xor(ss, 32);
      float rr = rsqrtf(ss * 0.0625f + EPS);
      bf16x4 outp;
      #pragma unroll
      for (int r = 0; r < 4; r++) outp[r] = (bf16)(dff[r] * rr * hwv[r]);
      long rowg = (long)zc * ROWS + (long)b * Lq + pr * 32 + tile * 16 + lm;
      *(bf16x4*)(dc + rowg * 128 + head * 16 + lq * 4) = outp;
    }
  }
}

// ---------------- seg + pool fused: 16 bins, 1-wave blocks ----------------
__global__ __launch_bounds__(64) void k_segpool(const bf16* __restrict__ h,
    const bf16* __restrict__ op, const float* __restrict__ segw,
    const float* __restrict__ rw, float* __restrict__ part) {
  int lp = blockIdx.x, b = blockIdx.y, ch = blockIdx.z;
  int t = threadIdx.x;
  int c0 = t * 2;
  float w0 = segw[ch * 128 + c0], w1 = segw[ch * 128 + c0 + 1];
  float rwv = rw[b * 8 + ch];
  float a0 = 0.f, a1 = 0.f;
  for (int l = 0; l < 36; l++) {
    int row = b * Lq + lp * 36 + l;
    const bf16* oprow = op + (long)ch * ROWS * CW + (long)row * CW;
    bf16x2 yv = *(const bf16x2*)(oprow + c0);
    float y0 = (float)yv[0], y1 = (float)yv[1];
    float ss = y0 * y0 + y1 * y1;
    #pragma unroll
    for (int m = 1; m < 64; m <<= 1) ss += __shfl_xor(ss, m);
    float r = rsqrtf(ss * (1.f / 128.f) + EPS);
    bf16x2 hv = *(const bf16x2*)(h + (long)row * WIDTH + ch * 128 + c0);
    a0 += ((float)hv[0] + y0 * r * w0) * rwv;
    a1 += ((float)hv[1] + y1 * r * w1) * rwv;
  }
  float* dst = part + ((long)b * 16 + lp) * 1024 + ch * 128 + c0;
  dst[0] = a0; dst[1] = a1;
}

// ---------------- head (reads 16 pool partials) ----------------
__global__ __launch_bounds__(256) void k_head(const float* __restrict__ part,
    const float* __restrict__ hw, const float* __restrict__ hb, float* __restrict__ out) {
  __shared__ float pool[1024];
  __shared__ float red[256];
  int b = blockIdx.x, t = threadIdx.x;
  for (int c = t; c < 1024; c += 256) {
    float a = 0.f;
    #pragma unroll
    for (int lp = 0; lp < 16; lp++) a += part[((long)b * 16 + lp) * 1024 + c];
    pool[c] = a * (1.f / 576.f);
  }
  __syncthreads();
  int j = t & 15, pt = t >> 4;
  float acc = 0.f;
  if (j < 10)
    for (int c = pt * 64; c < pt * 64 + 64; c++)
      acc += pool[c] * hw[c * 10 + j];
  red[t] = acc;
  __syncthreads();
  if (t < 10) {
    float a = hb[t];
    for (int p = 0; p < 16; p++) a += red[p * 16 + t];
    out[b * 10 + t] = a;
  }
}

// ---------------- launcher ----------------
extern "C" void kernel_launch(void* const* d_in, const int* in_sizes, int n_in,
                              void* d_out, int out_size, void* d_ws, size_t ws_size,
                              hipStream_t stream) {
  const float* x          = (const float*)d_in[0];
  const float* pixel_embed= (const float*)d_in[2];
  const float* freq_h     = (const float*)d_in[3];
  const float* freq_w     = (const float*)d_in[4];
  const float* phase_h    = (const float*)d_in[5];
  const float* phase_w    = (const float*)d_in[6];
  const float* pos_proj_w = (const float*)d_in[7];
  const float* pos_proj_b = (const float*)d_in[8];
  const float* embed_norm = (const float*)d_in[9];
  const float* se_w1      = (const float*)d_in[10];
  const float* se_b1      = (const float*)d_in[11];
  const float* se_w2      = (const float*)d_in[12];
  const float* se_b2      = (const float*)d_in[13];
  const float* mix_norm   = (const float*)d_in[14];
  const float* mlp_w1     = (const float*)d_in[15];
  const float* mlp_b1     = (const float*)d_in[16];
  const float* mlp_w2     = (const float*)d_in[17];
  const float* mlp_b2     = (const float*)d_in[18];
  const float* mlp_norm   = (const float*)d_in[19];
  const float* router_w   = (const float*)d_in[20];
  const float* router_b   = (const float*)d_in[21];
  const float* qkv_w      = (const float*)d_in[22];
  const float* qkv_b      = (const float*)d_in[23];
  const float* q_norm_w   = (const float*)d_in[24];
  const float* k_norm_w   = (const float*)d_in[25];
  const float* head_norm_w= (const float*)d_in[26];
  const float* lam_q1     = (const float*)d_in[27];
  const float* lam_k1     = (const float*)d_in[28];
  const float* lam_q2     = (const float*)d_in[29];
  const float* lam_k2     = (const float*)d_in[30];
  const float* out_w      = (const float*)d_in[31];
  const float* out_b      = (const float*)d_in[32];
  const float* seg_norm_w = (const float*)d_in[33];
  const float* head_w     = (const float*)d_in[34];
  const float* head_b     = (const float*)d_in[35];

  char* W = (char*)d_ws;
  bf16*  HB    = (bf16*)(W + B_HB);
  bf16*  G2B   = (bf16*)(W + B_G2B);
  float* POS   = (float*)(W + B_G2B);      // POS lives in G2B region (dead until MLP)
  bf16*  ENCB  = (bf16*)(W + B_ENCB);
  bf16*  POSWT = (bf16*)(W + B_POSWT);
  bf16*  QKVWT = (bf16*)(W + B_QKVWT);
  bf16*  OWT   = (bf16*)(W + B_OWT);
  float* SE    = (float*)(W + B_SE);
  float* T1    = (float*)(W + B_T1);
  float* MP    = (float*)(W + B_MP);
  float* RW    = (float*)(W + B_RW);
  float* LAM   = (float*)(W + B_LAM);
  char*  P     = W + B_POOL;
  bf16*  W1T   = (bf16*)P;
  bf16*  W2T   = (bf16*)(P + 8388608);
  bf16*  HID   = (bf16*)(P + 16777216);
  bf16*  PART1 = (bf16*)(P + 16777216 + 37748736);   // after full-width HID
  bf16*  QKV   = (bf16*)P;
  bf16*  DC    = (bf16*)(P + 28311552);
  float* out   = (float*)d_out;
  const int tier = (ws_size >= WS_BIG2) ? 2 : (ws_size >= WS_BIG) ? 1 : 0;

  // 0. all weight casts in one dispatch
  k_tcast_all<<<8832, 256, 0, stream>>>(mlp_w1, mlp_w2, pos_proj_w, qkv_w, out_w,
                                        W1T, W2T, POSWT, QKVWT, OWT);
  // 1. positional encoding + projection (POS f32 in G2B region)
  k_enc_b<<<288, 256, 0, stream>>>(freq_h, freq_w, phase_h, phase_w, ENCB);
  gemm64<0, 0, 0, 0><<<dim3(8, 10, 1), 256, 0, stream>>>(
      ENCB, 128, 0, POSWT, 128, 0, pos_proj_b, 0, POS, 1024, 0, 640, 1024, 128,
      nullptr, nullptr);
  // 2. embed + rmsnorm -> bf16 h
  k_embed<<<ROWS, 256, 0, stream>>>(x, pixel_embed, POS, embed_norm, HB);
  // 3. SE gate
  k_meanl_p<<<dim3(16, 8), 256, 0, stream>>>(HB, MP);
  k_se1<<<dim3(32, 8), 256, 0, stream>>>(MP, se_w1, se_b1, T1);
  k_se2<<<dim3(32, 8), 256, 0, stream>>>(T1, se_w2, se_b2, SE);
  k_mix_b<<<ROWS, 256, 0, stream>>>(HB, SE, mix_norm);
  // 4. MLP
  if (tier == 2) {
    // gemm1: full-width HID, z = 2 N-halves (1152 blocks)
    gemm_bt<1, 1><<<dim3(16, 36, 2), 256, 0, stream>>>(
        HB, 1024, 0, W1T, 1024, 2048L * 1024, mlp_b1, 2048,
        HID, 4096, 2048, 4608, 2048, 1024);
    // gemm2: 128x128 tiles, z = 2 K-split into two bf16 partial buffers (576 blocks,
    // 16 MFMA/barrier). bias deferred to k_addnorm2.
    gemm_bt<0, 1><<<dim3(8, 36, 2), 256, 0, stream>>>(
        HID, 4096, 2048, W2T, 4096, 2048, nullptr, 0,
        G2B, 1024, (long)(PART1 - G2B), 4608, 1024, 2048);
    k_addnorm2<<<ROWS, 256, 0, stream>>>(HB, G2B, PART1, mlp_b2, mlp_norm);
  } else if (tier == 1) {
    gemm_bt<1, 1><<<dim3(16, 36, 2), 256, 0, stream>>>(
        HB, 1024, 0, W1T, 1024, 2048L * 1024, mlp_b1, 2048,
        HID, 4096, 2048, 4608, 2048, 1024);
    gemm64<0, 1, 0, 0><<<dim3(8, 72, 1), 256, 0, stream>>>(
        HID, 4096, 0, W2T, 4096, 0, mlp_b2, 0,
        G2B, 1024, 0, 4608, 1024, 4096, nullptr, nullptr);
    k_addnorm_b<<<ROWS, 256, 0, stream>>>(HB, G2B, mlp_norm);
  } else {
    gemm_bt<1, 1><<<dim3(16, 36, 1), 256, 0, stream>>>(
        HB, 1024, 0, W1T, 1024, 0, mlp_b1, 0, HID, 2048, 0, 4608, 2048, 1024);
    gemm64<0, 1, 0, 0><<<dim3(8, 72, 1), 256, 0, stream>>>(
        HID, 2048, 0, W2T, 4096, 0, mlp_b2, 0, G2B, 1024, 0, 4608, 1024, 2048,
        nullptr, nullptr);
    gemm_bt<1, 1><<<dim3(16, 36, 1), 256, 0, stream>>>(
        HB, 1024, 0, W1T + 2048L * 1024, 1024, 0, mlp_b1 + 2048, 0, HID, 2048, 0,
        4608, 2048, 1024);
    gemm64<0, 1, 1, 0><<<dim3(8, 72, 1), 256, 0, stream>>>(
        HID, 2048, 0, W2T + 2048, 4096, 0, nullptr, 0, G2B, 1024, 0,
        4608, 1024, 2048, nullptr, nullptr);
    k_addnorm_b<<<ROWS, 256, 0, stream>>>(HB, G2B, mlp_norm);
  }
  // 5. router + lambdas
  k_meanl_p<<<dim3(16, 8), 256, 0, stream>>>(HB, MP);
  k_router<<<8, 256, 0, stream>>>(MP, router_w, router_b,
                                  lam_q1, lam_k1, lam_q2, lam_k2, RW, LAM);
  // 6. qkv-proj with fused silu + Q/K rmsnorm (+ Q prescale) in epilogue
  gemm64<1, 1, 0, 1><<<dim3(3, 72, 8), 256, 0, stream>>>(
      HB, 1024, CW, QKVWT, 128, 384 * 128, qkv_b, 384,
      QKV, 384, (long)ROWS * 384, ROWS, 384, 128, q_norm_w, k_norm_w);
  // 7. attention (prenormed), out-proj in-place on DC
  k_attn_mfma<<<dim3(64, 2, 8), 256, 0, stream>>>(QKV, LAM, head_norm_w, DC);
  gemm64<1, 1, 0, 0><<<dim3(1, 72, 8), 256, 0, stream>>>(
      DC, 128, (long)ROWS * 128, OWT, 128, 128 * 128, out_b, 128,
      DC, 128, (long)ROWS * 128, ROWS, 128, 128, nullptr, nullptr);
  // 8. seg + pool fused -> 16 partials; head folds the final reduce
  k_segpool<<<dim3(16, 8, 8), 64, 0, stream>>>(HB, DC, seg_norm_w, RW, MP);
  k_head<<<8, 256, 0, stream>>>(MP, head_w, head_b, out);
}

// Round 11
// 440.859 us; speedup vs baseline: 1.1417x; 1.0263x over previous
//
#include <hip/hip_runtime.h>
#include <math.h>

typedef __bf16 bf16;
typedef __bf16 bf16x8 __attribute__((ext_vector_type(8)));
typedef __bf16 bf16x4 __attribute__((ext_vector_type(4)));
typedef __bf16 bf16x2 __attribute__((ext_vector_type(2)));
typedef float f32x4 __attribute__((ext_vector_type(4)));
typedef short s16x4 __attribute__((ext_vector_type(4)));

// ---------------- constants ----------------
constexpr int Bsz = 8, HIMG = 24, WIMG = 24;
constexpr int Lq = 576;
constexpr int WIDTH = 1024, NCH = 8, CW = 128;
constexpr int NHEADS = 8, HD = 16, HALF = 8;
constexpr float EPS = 1e-6f;
constexpr float LAMINIT = 0.2f;
// 1/sqrt(8) * log2(e): scores exit MFMA in log2 domain -> v_exp_f32 directly
constexpr float QSCALE_E = 0.35355339059327373f * 1.4426950408889634f;
constexpr int ROWS = Bsz * Lq;              // 4608
constexpr long PSTRIDE = 4718592;           // bf16 elements per MLP partial buffer

__device__ __forceinline__ float fexp2(float x) {
#if __has_builtin(__builtin_amdgcn_exp2f)
  return __builtin_amdgcn_exp2f(x);
#else
  return exp2f(x);
#endif
}

// ---------------- workspace byte offsets ----------------
constexpr size_t B_HB    = 0;                        // bf16 h [4608][1024]
constexpr size_t B_G2B   = B_HB    + 9437184;        // bf16 g2/partial0; POS f32 early
constexpr size_t B_ENCB  = B_G2B   + 9437184;        // bf16 enc [640][128]
constexpr size_t B_POSWT = B_ENCB  + 163840;         // bf16 [1024][128]
constexpr size_t B_QKVWT = B_POSWT + 262144;         // bf16 [8][384][128]
constexpr size_t B_OWT   = B_QKVWT + 786432;         // bf16 [8][128][128]
constexpr size_t B_SE    = B_OWT   + 262144;         // f32 [8][1024]
constexpr size_t B_T1    = B_SE    + 32768;          // f32 [8][256]
constexpr size_t B_MP    = B_T1    + 8192;           // f32 [8][16][1024]
constexpr size_t B_RW    = B_MP    + 524288;         // f32 [64]
constexpr size_t B_LAM   = B_RW    + 256;            // f32 [8]
constexpr size_t B_POOL  = B_LAM   + 256;            // = 20914688; phase-shared pool
// pool (MLP small): W1T 8388608 | W2T 8388608 | HID 18874368            (58.7 MB)
// pool (MLP big):   W1T 8388608 | W2T 8388608 | HID 37748736            (75.4 MB)
// pool (MLP big2):  ... + PART1 bf16 9437184 after HID                  (84.9 MB)
// pool (MLP big3):  ... + PARTS bf16 4x9437184 after HID                (113.2 MB)
// pool (chan):      QKV 28311552 | DC 9437184 (out-proj IN-PLACE on DC) (58.7 MB)
constexpr size_t WS_BIG  = B_POOL + 8388608 + 8388608 + 37748736;     // 75440640
constexpr size_t WS_BIG2 = WS_BIG + 9437184;                          // 84877824
constexpr size_t WS_BIG3 = WS_BIG + 4 * 9437184;                      // 113189376

// ---------------- helpers ----------------
__device__ __forceinline__ float blockReduceSum256(float v, float* red) {
  #pragma unroll
  for (int off = 32; off; off >>= 1) v += __shfl_down(v, off, 64);
  int lane = threadIdx.x & 63, wid = threadIdx.x >> 6;
  if (lane == 0) red[wid] = v;
  __syncthreads();
  float total = 0.f;
  #pragma unroll
  for (int i = 0; i < 4; i++) total += red[i];
  return total;
}
__device__ __forceinline__ float silu(float x) { return x / (1.f + __expf(-x)); }

__device__ __forceinline__ void gl16(const bf16* g, bf16* l) {
  __builtin_amdgcn_global_load_lds(
      (const __attribute__((address_space(1))) void*)g,
      (__attribute__((address_space(3))) void*)l, 16, 0, 0);
}

// v_mfma_f32_16x16x16_bf16 wrapper (A,B = 4 bf16/lane; k = quad*4+j)
__device__ __forceinline__ f32x4 mfma16(bf16x4 a, bf16x4 b, f32x4 c) {
#if __has_builtin(__builtin_amdgcn_mfma_f32_16x16x16bf16_1k)
  union { bf16x4 h; s16x4 s; } ua, ub;
  ua.h = a; ub.h = b;
  return __builtin_amdgcn_mfma_f32_16x16x16bf16_1k(ua.s, ub.s, c, 0, 0, 0);
#else
  f32x4 d = c;
  asm volatile("v_mfma_f32_16x16x16_bf16 %0, %1, %2, %0"
               : "+v"(d) : "v"(a), "v"(b));
  return d;
#endif
}

// ---------------- batched cast+transpose of ALL weights, one dispatch -------------
__device__ __forceinline__ void tcast_tile(const float* __restrict__ W,
    bf16* __restrict__ Wt, int K, int N, long zo, int bx, int by) {
  __shared__ float t[32][33];
  int n0 = bx * 32, k0 = by * 32;
  int tid = threadIdx.x;
  int r = tid >> 3, c4 = (tid & 7) * 4;
  const float4 v = *(const float4*)(W + zo + (long)(k0 + r) * N + n0 + c4);
  t[c4 + 0][r] = v.x; t[c4 + 1][r] = v.y; t[c4 + 2][r] = v.z; t[c4 + 3][r] = v.w;
  __syncthreads();
  bf16* dst = Wt + zo + (long)(n0 + r) * K + k0 + c4;
  dst[0] = (bf16)t[r][c4 + 0]; dst[1] = (bf16)t[r][c4 + 1];
  dst[2] = (bf16)t[r][c4 + 2]; dst[3] = (bf16)t[r][c4 + 3];
}

__global__ __launch_bounds__(256) void k_tcast_all(
    const float* __restrict__ w1, const float* __restrict__ w2,
    const float* __restrict__ posw, const float* __restrict__ qkvw,
    const float* __restrict__ outw,
    bf16* __restrict__ W1T, bf16* __restrict__ W2T, bf16* __restrict__ POSWT,
    bf16* __restrict__ QKVWT, bf16* __restrict__ OWT) {
  int bid = blockIdx.x;
  if (bid < 4096) {
    tcast_tile(w1, W1T, 1024, 4096, 0, bid % 128, bid / 128);
  } else if (bid < 8192) {
    int t = bid - 4096;
    tcast_tile(w2, W2T, 4096, 1024, 0, t % 32, t / 32);
  } else if (bid < 8320) {
    int t = bid - 8192;
    tcast_tile(posw, POSWT, 128, 1024, 0, t % 32, t / 32);
  } else if (bid < 8704) {
    int t = bid - 8320;
    int z = t / 48; t -= z * 48;
    tcast_tile(qkvw, QKVWT, 128, 384, (long)z * 49152, t % 12, t / 12);
  } else {
    int t = bid - 8704;
    int z = t / 16; t -= z * 16;
    tcast_tile(outw, OWT, 128, 128, (long)z * 16384, t % 4, t / 4);
  }
}

// ---------------- positional encoding (bf16 out) ----------------
__global__ void k_enc_b(const float* __restrict__ fh, const float* __restrict__ fw,
                        const float* __restrict__ ph, const float* __restrict__ pw,
                        bf16* __restrict__ enc) {
  int idx = blockIdx.x * blockDim.x + threadIdx.x;
  if (idx >= Lq * 128) return;
  int l = idx >> 7, c = idx & 127;
  int hh = l / WIMG, ww = l % WIMG;
  float v;
  if (c < 64) {
    int f = c & 31;
    float fr = log1pf(__expf(fh[f])) * 10.f;
    float a = (hh / (float)HIMG) * fr + ph[f];
    v = (c < 32) ? sinf(a) : cosf(a);
  } else {
    int f = c & 31;
    float fr = log1pf(__expf(fw[f])) * 10.f;
    float a = (ww / (float)WIMG) * fr + pw[f];
    v = (c < 96) ? sinf(a) : cosf(a);
  }
  enc[idx] = (bf16)v;
}

// ---------------- bf16 MFMA GEMM 128x128 ----------------
// SWZ=0: 3D grid (x=n, y=m, z).  SWZ=1 (gemm1): 1D grid 1152; XCD-pinned groups
// (m, n-half): all 16 n-tiles of a group share lid%8 -> same XCD L2 serves A-panel.
// SWZ=2 (gemm2 K-split): 1D grid 8*G; group G=(m,z) owns its 8 n-tiles on one XCD.
template <int ACT, int OUTBF, int SWZ>
__global__ __launch_bounds__(256) void gemm_bt(
    const bf16* __restrict__ A, int lda, long aZs,
    const bf16* __restrict__ Bt, int ldb, long bZs,
    const float* __restrict__ bias, int biasZs,
    void* __restrict__ Cv, int ldc, long cZs,
    int M, int N, int K) {
  __shared__ bf16 As[128 * 32];
  __shared__ bf16 Bs[128 * 32];
  int tid = threadIdx.x;
  int m0, n0, z;
  if constexpr (SWZ == 0) {
    m0 = blockIdx.y * 128; n0 = blockIdx.x * 128; z = blockIdx.z;
  } else if constexpr (SWZ == 1) {
    int lid = blockIdx.x;
    int xcd = lid & 7, idx = lid >> 3;
    int j = idx & 15, G = xcd + 8 * (idx >> 4);   // G in [0,72)
    m0 = (G % 36) * 128; n0 = ((G / 36) * 16 + j) * 128; z = 0;
  } else {
    int lid = blockIdx.x;
    int xcd = lid & 7, idx = lid >> 3;
    int n = idx & 7, G = xcd + 8 * (idx >> 3);    // G in [0, grid/8)
    m0 = (G % 36) * 128; n0 = n * 128; z = G / 36;
  }
  const bf16* Ab = A + (long)z * aZs;
  const bf16* Bb = Bt + (long)z * bZs;
  f32x4 acc[4][4] = {};
  int wv = tid >> 6, lane = tid & 63;
  int wrow = (wv >> 1) * 64, wcol = (wv & 1) * 64;
  int lm = lane & 15, lq = lane >> 4;
  const bf16* ag = Ab + (long)(m0 + (tid >> 2)) * lda + (tid & 3) * 8;
  const bf16* bg = Bb + (long)(n0 + (tid >> 2)) * ldb + (tid & 3) * 8;
  bf16* asd = As + tid * 8;
  bf16* bsd = Bs + tid * 8;
  for (int k0 = 0; k0 < K; k0 += 32) {
    gl16(ag + k0, asd);
    gl16(ag + k0 + 64L * lda, asd + 2048);
    gl16(bg + k0, bsd);
    gl16(bg + k0 + 64L * ldb, bsd + 2048);
    __syncthreads();
    bf16x8 af[4], bfr[4];
    #pragma unroll
    for (int i = 0; i < 4; i++) {
      af[i]  = *(const bf16x8*)(As + (wrow + i * 16 + lm) * 32 + lq * 8);
      bfr[i] = *(const bf16x8*)(Bs + (wcol + i * 16 + lm) * 32 + lq * 8);
    }
    #pragma unroll
    for (int i = 0; i < 4; i++)
      #pragma unroll
      for (int j = 0; j < 4; j++)
        acc[i][j] = __builtin_amdgcn_mfma_f32_16x16x32_bf16(af[i], bfr[j], acc[i][j], 0, 0, 0);
    __syncthreads();
  }
  long cz = (long)z * cZs;
  const float* bz = bias ? bias + (long)z * biasZs : nullptr;
  #pragma unroll
  for (int i = 0; i < 4; i++) {
    int row = m0 + wrow + i * 16 + lq * 4;
    #pragma unroll
    for (int j = 0; j < 4; j++) {
      int col = n0 + wcol + j * 16 + lm;
      float bv = bz ? bz[col] : 0.f;
      #pragma unroll
      for (int r = 0; r < 4; r++) {
        float v = acc[i][j][r] + bv;
        if (ACT == 1) v = silu(v);
        long off = cz + (long)(row + r) * ldc + col;
        if (OUTBF) ((bf16*)Cv)[off] = (bf16)v;
        else       ((float*)Cv)[off] = v;
      }
    }
  }
}

// ---------------- bf16 MFMA GEMM 64x128 tile ----------------
// NORM=1 (qkv mode): after silu, 8-col-group rmsnorm for Q (x==0, qn, prescale) and
// K (x==1, kn); V (x==2) passthrough.
template <int ACT, int OUTBF, int ACC, int NORM>
__global__ __launch_bounds__(256) void gemm64(
    const bf16* __restrict__ A, int lda, long aZs,
    const bf16* __restrict__ Bt, int ldb, long bZs,
    const float* __restrict__ bias, int biasZs,
    void* __restrict__ Cv, int ldc, long cZs,
    int M, int N, int K,
    const float* __restrict__ qn, const float* __restrict__ kn) {
  __shared__ bf16 As[64 * 32];
  __shared__ bf16 Bs[128 * 32];
  int tid = threadIdx.x;
  int m0 = blockIdx.y * 64, n0 = blockIdx.x * 128;
  int z = blockIdx.z;
  const bf16* Ab = A + (long)z * aZs;
  const bf16* Bb = Bt + (long)z * bZs;
  f32x4 acc[4][2] = {};
  int wv = tid >> 6, lane = tid & 63;
  int lm = lane & 15, lq = lane >> 4;
  int wcol = wv * 32;
  const bf16* ag = Ab + (long)(m0 + (tid >> 2)) * lda + (tid & 3) * 8;
  const bf16* bg = Bb + (long)(n0 + (tid >> 2)) * ldb + (tid & 3) * 8;
  bf16* asd = As + tid * 8;
  bf16* bsd = Bs + tid * 8;
  for (int k0 = 0; k0 < K; k0 += 32) {
    gl16(ag + k0, asd);
    gl16(bg + k0, bsd);
    gl16(bg + k0 + 64L * ldb, bsd + 2048);
    __syncthreads();
    bf16x8 af[4], bfr[2];
    #pragma unroll
    for (int i = 0; i < 4; i++)
      af[i] = *(const bf16x8*)(As + (i * 16 + lm) * 32 + lq * 8);
    #pragma unroll
    for (int j = 0; j < 2; j++)
      bfr[j] = *(const bf16x8*)(Bs + (wcol + j * 16 + lm) * 32 + lq * 8);
    #pragma unroll
    for (int i = 0; i < 4; i++)
      #pragma unroll
      for (int j = 0; j < 2; j++)
        acc[i][j] = __builtin_amdgcn_mfma_f32_16x16x32_bf16(af[i], bfr[j], acc[i][j], 0, 0, 0);
    __syncthreads();
  }
  long cz = (long)z * cZs;
  const float* bz = bias ? bias + (long)z * biasZs : nullptr;
  if constexpr (NORM == 0) {
    #pragma unroll
    for (int i = 0; i < 4; i++) {
      int row = m0 + i * 16 + lq * 4;
      #pragma unroll
      for (int j = 0; j < 2; j++) {
        int col = n0 + wcol + j * 16 + lm;
        float bv = bz ? bz[col] : 0.f;
        #pragma unroll
        for (int r = 0; r < 4; r++) {
          float v = acc[i][j][r] + bv;
          long off = cz + (long)(row + r) * ldc + col;
          if (ACC) v += (float)((bf16*)Cv)[off];
          if (ACT == 1) v = silu(v);
          if (OUTBF) ((bf16*)Cv)[off] = (bf16)v;
          else       ((float*)Cv)[off] = v;
        }
      }
    }
  } else {
    int nsec = blockIdx.x;              // 0=Q, 1=K, 2=V
    bool don = nsec < 2;
    float wnv = 1.f;
    if (nsec == 0) wnv = qn[z * 8 + (lm & 7)] * QSCALE_E;
    else if (nsec == 1) wnv = kn[z * 8 + (lm & 7)];
    #pragma unroll
    for (int i = 0; i < 4; i++) {
      int row = m0 + i * 16 + lq * 4;
      #pragma unroll
      for (int j = 0; j < 2; j++) {
        int col = n0 + wcol + j * 16 + lm;
        float bv = bz ? bz[col] : 0.f;
        #pragma unroll
        for (int r = 0; r < 4; r++) {
          float v = acc[i][j][r] + bv;
          if (ACT == 1) v = silu(v);
          float s = v * v;
          s += __shfl_xor(s, 1);
          s += __shfl_xor(s, 2);
          s += __shfl_xor(s, 4);
          if (don) v = v * rsqrtf(s * 0.125f + EPS) * wnv;
          ((bf16*)Cv)[cz + (long)(row + r) * ldc + col] = (bf16)v;
        }
      }
    }
  }
}

// ---------------- embed + rmsnorm -> bf16 h ----------------
__global__ __launch_bounds__(256) void k_embed(const float* __restrict__ x,
    const float* __restrict__ emb, const float* __restrict__ pos,
    const float* __restrict__ nw, bf16* __restrict__ h) {
  __shared__ float red[4];
  int row = blockIdx.x;
  int l = row % Lq;
  int xi = (int)(x[row] * 255.f);
  xi = min(max(xi, 0), 255);
  const float* er = emb + (long)xi * WIDTH;
  const float* pr = pos + (long)l * WIDTH;
  int c0 = threadIdx.x * 4;
  float v[4]; float ss = 0.f;
  #pragma unroll
  for (int i = 0; i < 4; i++) { v[i] = er[c0 + i] + pr[c0 + i]; ss += v[i] * v[i]; }
  ss = blockReduceSum256(ss, red);
  float r = rsqrtf(ss / WIDTH + EPS);
  bf16* hr = h + (long)row * WIDTH;
  #pragma unroll
  for (int i = 0; i < 4; i++) hr[c0 + i] = (bf16)(v[i] * r * nw[c0 + i]);
}

// ---------------- mean over L, phase 1: 16 partials per b ----------------
__global__ void k_meanl_p(const bf16* __restrict__ h, float* __restrict__ part) {
  int lp = blockIdx.x, b = blockIdx.y, t = threadIdx.x;
  const bf16* p = h + ((long)b * Lq + (long)lp * 36) * WIDTH + t * 4;
  float a0 = 0, a1 = 0, a2 = 0, a3 = 0;
  for (int l = 0; l < 36; l++) {
    bf16x4 v = *(const bf16x4*)(p + (long)l * WIDTH);
    a0 += (float)v[0]; a1 += (float)v[1]; a2 += (float)v[2]; a3 += (float)v[3];
  }
  float* dst = part + ((long)b * 16 + lp) * WIDTH + t * 4;
  dst[0] = a0; dst[1] = a1; dst[2] = a2; dst[3] = a3;
}

// ---------------- SE phase 1 ----------------
__global__ __launch_bounds__(256) void k_se1(const float* __restrict__ part,
    const float* __restrict__ w1, const float* __restrict__ b1,
    float* __restrict__ t1) {
  __shared__ float sv[1024];
  __shared__ float red[256];
  int jb = blockIdx.x, b = blockIdx.y, t = threadIdx.x;
  for (int c = t; c < 1024; c += 256) {
    float a = 0.f;
    #pragma unroll
    for (int lp = 0; lp < 16; lp++) a += part[((long)b * 16 + lp) * 1024 + c];
    sv[c] = a * (1.f / 576.f);
  }
  __syncthreads();
  int j = t & 7, pt = t >> 3;
  int j0 = jb * 8;
  float acc = 0.f;
  int c0 = pt * 32;
  #pragma unroll 8
  for (int c = c0; c < c0 + 32; c++) acc += sv[c] * w1[c * 256 + j0 + j];
  red[t] = acc;
  __syncthreads();
  if (t < 8) {
    float a = b1[j0 + t];
    #pragma unroll
    for (int p = 0; p < 32; p++) a += red[p * 8 + t];
    t1[b * 256 + j0 + t] = silu(a);
  }
}

// ---------------- SE phase 2 ----------------
__global__ __launch_bounds__(256) void k_se2(const float* __restrict__ t1,
    const float* __restrict__ w2, const float* __restrict__ b2,
    float* __restrict__ s) {
  __shared__ float red[256];
  int jb = blockIdx.x, b = blockIdx.y, t = threadIdx.x;
  int j = t & 31, pt = t >> 5;
  int j0 = jb * 32;
  const float* tb = t1 + b * 256;
  float acc = 0.f;
  int c0 = pt * 32;
  #pragma unroll 8
  for (int c = c0; c < c0 + 32; c++) acc += tb[c] * w2[c * 1024 + j0 + j];
  red[t] = acc;
  __syncthreads();
  if (t < 32) {
    float a = b2[j0 + t];
    #pragma unroll
    for (int p = 0; p < 8; p++) a += red[p * 32 + t];
    s[b * 1024 + j0 + t] = 1.f / (1.f + __expf(-a));
  }
}

// ---------------- mix: h += rmsnorm(h*(s-1), mw) ----------------
__global__ __launch_bounds__(256) void k_mix_b(bf16* __restrict__ h,
    const float* __restrict__ s, const float* __restrict__ mw) {
  __shared__ float red[4];
  int row = blockIdx.x;
  int b = row / Lq;
  bf16* hr = h + (long)row * WIDTH;
  const float* sb = s + b * WIDTH;
  int c0 = threadIdx.x * 4;
  float hv[4], y[4]; float ss = 0.f;
  #pragma unroll
  for (int i = 0; i < 4; i++) {
    hv[i] = (float)hr[c0 + i];
    y[i] = hv[i] * (sb[c0 + i] - 1.f); ss += y[i] * y[i];
  }
  ss = blockReduceSum256(ss, red);
  float r = rsqrtf(ss / WIDTH + EPS);
  #pragma unroll
  for (int i = 0; i < 4; i++) hr[c0 + i] = (bf16)(hv[i] + y[i] * r * mw[c0 + i]);
}

// ---------------- h += rmsnorm(g, mw) ----------------
__global__ __launch_bounds__(256) void k_addnorm_b(bf16* __restrict__ h,
    const bf16* __restrict__ g, const float* __restrict__ mw) {
  __shared__ float red[4];
  int row = blockIdx.x;
  bf16* hr = h + (long)row * WIDTH;
  const bf16* gr = g + (long)row * WIDTH;
  int c0 = threadIdx.x * 4;
  float y[4]; float ss = 0.f;
  #pragma unroll
  for (int i = 0; i < 4; i++) { y[i] = (float)gr[c0 + i]; ss += y[i] * y[i]; }
  ss = blockReduceSum256(ss, red);
  float r = rsqrtf(ss / WIDTH + EPS);
  #pragma unroll
  for (int i = 0; i < 4; i++)
    hr[c0 + i] = (bf16)((float)hr[c0 + i] + y[i] * r * mw[c0 + i]);
}

// ---------------- h += rmsnorm(p0 + p1 + b2, mw)  (2-way K-split partials) --------
__global__ __launch_bounds__(256) void k_addnorm2(bf16* __restrict__ h,
    const bf16* __restrict__ p0, const bf16* __restrict__ p1,
    const float* __restrict__ b2, const float* __restrict__ mw) {
  __shared__ float red[4];
  int row = blockIdx.x;
  bf16* hr = h + (long)row * WIDTH;
  const bf16* g0 = p0 + (long)row * WIDTH;
  const bf16* g1 = p1 + (long)row * WIDTH;
  int c0 = threadIdx.x * 4;
  float y[4]; float ss = 0.f;
  #pragma unroll
  for (int i = 0; i < 4; i++) {
    y[i] = (float)g0[c0 + i] + (float)g1[c0 + i] + b2[c0 + i];
    ss += y[i] * y[i];
  }
  ss = blockReduceSum256(ss, red);
  float r = rsqrtf(ss / WIDTH + EPS);
  #pragma unroll
  for (int i = 0; i < 4; i++)
    hr[c0 + i] = (bf16)((float)hr[c0 + i] + y[i] * r * mw[c0 + i]);
}

// ---------------- h += rmsnorm(p0+p1+p2+p3 + b2, mw)  (4-way K-split) -------------
__global__ __launch_bounds__(256) void k_addnorm4(bf16* __restrict__ h,
    const bf16* __restrict__ parts, const float* __restrict__ b2,
    const float* __restrict__ mw) {
  __shared__ float red[4];
  int row = blockIdx.x;
  bf16* hr = h + (long)row * WIDTH;
  const bf16* g0 = parts + (long)row * WIDTH;
  int c0 = threadIdx.x * 4;
  float y[4]; float ss = 0.f;
  #pragma unroll
  for (int i = 0; i < 4; i++) {
    float a = b2[c0 + i];
    #pragma unroll
    for (int p = 0; p < 4; p++) a += (float)g0[(long)p * PSTRIDE + c0 + i];
    y[i] = a; ss += a * a;
  }
  ss = blockReduceSum256(ss, red);
  float r = rsqrtf(ss / WIDTH + EPS);
  #pragma unroll
  for (int i = 0; i < 4; i++)
    hr[c0 + i] = (bf16)((float)hr[c0 + i] + y[i] * r * mw[c0 + i]);
}

// ---------------- router + lambdas ----------------
__global__ __launch_bounds__(256) void k_router(const float* __restrict__ part,
    const float* __restrict__ rwgt, const float* __restrict__ rb,
    const float* __restrict__ lq1, const float* __restrict__ lk1,
    const float* __restrict__ lq2, const float* __restrict__ lk2,
    float* __restrict__ rw, float* __restrict__ lam) {
  __shared__ float sv[1024];
  __shared__ float red[256];
  __shared__ float lg[8];
  int b = blockIdx.x, t = threadIdx.x;
  for (int c = t; c < 1024; c += 256) {
    float a = 0.f;
    #pragma unroll
    for (int lp = 0; lp < 16; lp++) a += part[((long)b * 16 + lp) * 1024 + c];
    sv[c] = a * (1.f / 576.f);
  }
  __syncthreads();
  int j = t & 7, pt = t >> 3;
  float acc = 0.f;
  int c0 = pt * 32;
  #pragma unroll 8
  for (int c = c0; c < c0 + 32; c++) acc += sv[c] * rwgt[c * 8 + j];
  red[t] = acc;
  __syncthreads();
  if (t < 8) {
    float a = rb[t];
    for (int p = 0; p < 32; p++) a += red[p * 8 + t];
    lg[t] = a;
  }
  __syncthreads();
  if (t == 0) {
    float v[8]; bool sel[8];
    #pragma unroll
    for (int i = 0; i < 8; i++) { v[i] = lg[i]; sel[i] = false; }
    int idxs[4]; float vals[4];
    for (int s = 0; s < 4; s++) {
      int bi = -1; float bv = -1e30f;
      for (int i = 0; i < 8; i++) if (!sel[i] && v[i] > bv) { bv = v[i]; bi = i; }
      sel[bi] = true; idxs[s] = bi; vals[s] = bv;
    }
    float m = vals[0], den = 0.f, e[4];
    for (int s = 0; s < 4; s++) { e[s] = __expf(vals[s] - m); den += e[s]; }
    for (int i = 0; i < 8; i++) rw[b * 8 + i] = 0.f;
    for (int s = 0; s < 4; s++) rw[b * 8 + idxs[s]] = e[s] / den;
  }
  if (b == 0 && t >= 8 && t < 16) {
    int c = t - 8;
    float d1 = 0.f, d2 = 0.f;
    for (int i = 0; i < 8; i++) {
      d1 += lq1[c * 8 + i] * lk1[c * 8 + i];
      d2 += lq2[c * 8 + i] * lk2[c * 8 + i];
    }
    lam[c] = __expf(d1) - __expf(d2) + LAMINIT;
  }
}

// ---------------- MFMA causal differential attention (prenormed Q/K) --------------
__global__ __launch_bounds__(256) void k_attn_mfma(
    const bf16* __restrict__ qkv, const float* __restrict__ lam,
    const float* __restrict__ hnw, bf16* __restrict__ dc) {
  __shared__ bf16 Ks[576 * 16];
  __shared__ bf16 Vt[16 * 584];
  int tid = threadIdx.x;
  int slice = blockIdx.x; int zc = slice >> 3, b = slice & 7;
  int head = blockIdx.z;
  const bf16* qkvb = qkv + ((long)zc * ROWS + (long)b * Lq) * 384;
  for (int i = tid; i < 1152; i += 256) {
    int row = i >> 1, hf = i & 1;
    gl16(qkvb + (long)row * 384 + 128 + head * 16 + hf * 8, Ks + i * 8);
  }
  for (int i = tid; i < 1152; i += 256) {
    int row = i >> 1, dh = i & 1;
    bf16x8 v = *(const bf16x8*)(qkvb + (long)row * 384 + 256 + head * 16 + dh * 8);
    #pragma unroll
    for (int j = 0; j < 8; j++) Vt[(dh * 8 + j) * 584 + row] = v[j];
  }
  __syncthreads();
  int wv = tid >> 6, lane = tid & 63;
  int lm = lane & 15, lq = lane >> 4;
  float lamv = lam[zc];
  float hwv[4];
  #pragma unroll
  for (int r = 0; r < 4; r++) hwv[r] = hnw[zc * 16 + lq * 4 + r] * (1.f - LAMINIT);
  int u = blockIdx.y * 4 + wv;
  int prA, prB, prC;
  if (u < 6) { prA = u + 2; prB = 17 - u; prC = -1; }
  else       { int v2 = u - 6; prA = v2; prB = 8 + v2; prC = 11 - v2; }
  for (int pi = 0; pi < 3; pi++) {
    int pr = (pi == 0) ? prA : (pi == 1) ? prB : prC;
    if (pr < 0) continue;
    bf16x8 bq0[2] = {{}, {}}, bq1[2] = {{}, {}};
    if (lq < 2) {
      #pragma unroll
      for (int tile = 0; tile < 2; tile++) {
        bf16x8 t8 = *(const bf16x8*)(
            qkvb + (long)(pr * 32 + tile * 16 + lm) * 384 + head * 16 + lq * 8);
        if (lq == 0) bq0[tile] = t8; else bq1[tile] = t8;
      }
    }
    f32x4 o[2][2] = {};
    float den[2][2] = {};
    for (int kc = 0; kc <= pr; kc++) {
      f32x4 sT[2][2][2] = {};
      #pragma unroll
      for (int t = 0; t < 2; t++) {
        bf16x8 aK = {};
        if (lq < 2) aK = *(const bf16x8*)(Ks + (kc * 32 + t * 16 + lm) * 16 + lq * 8);
        #pragma unroll
        for (int tile = 0; tile < 2; tile++) {
          sT[t][tile][0] = __builtin_amdgcn_mfma_f32_16x16x32_bf16(aK, bq0[tile], sT[t][tile][0], 0, 0, 0);
          sT[t][tile][1] = __builtin_amdgcn_mfma_f32_16x16x32_bf16(aK, bq1[tile], sT[t][tile][1], 0, 0, 0);
        }
      }
      bool diag = (kc == pr);
      #pragma unroll
      for (int t = 0; t < 2; t++) {
        bf16x4 aV = *(const bf16x4*)(Vt + lm * 584 + kc * 32 + t * 16 + lq * 4);
        #pragma unroll
        for (int tile = 0; tile < 2; tile++) {
          if (diag && tile == 0 && t == 1) continue;
          bool masked = diag && (tile == t);
          #pragma unroll
          for (int h2 = 0; h2 < 2; h2++) {
            bf16x4 pb;
            float dsum = 0.f;
            #pragma unroll
            for (int r = 0; r < 4; r++) {
              float ev = fexp2(sT[t][tile][h2][r]);
              if (masked && (lq * 4 + r > lm)) ev = 0.f;
              dsum += ev;
              pb[r] = (bf16)ev;
            }
            den[tile][h2] += dsum;
            o[tile][h2] = mfma16(aV, pb, o[tile][h2]);
          }
        }
      }
    }
    #pragma unroll
    for (int tile = 0; tile < 2; tile++)
      #pragma unroll
      for (int h2 = 0; h2 < 2; h2++) {
        den[tile][h2] += __shfl_xor(den[tile][h2], 16);
        den[tile][h2] += __shfl_xor(den[tile][h2], 32);
      }
    #pragma unroll
    for (int tile = 0; tile < 2; tile++) {
      float inv1 = 1.f / den[tile][0];
      float inv2 = lamv / den[tile][1];
      float dff[4]; float ss = 0.f;
      #pragma unroll
      for (int r = 0; r < 4; r++) {
        dff[r] = o[tile][0][r] * inv1 - o[tile][1][r] * inv2;
        ss += dff[r] * dff[r];
      }
      ss += __shfl_xor(ss, 16);
      ss += __shfl_xor(ss, 32);
      float rr = rsqrtf(ss * 0.0625f + EPS);
      bf16x4 outp;
      #pragma unroll
      for (int r = 0; r < 4; r++) outp[r] = (bf16)(dff[r] * rr * hwv[r]);
      long rowg = (long)zc * ROWS + (long)b * Lq + pr * 32 + tile * 16 + lm;
      *(bf16x4*)(dc + rowg * 128 + head * 16 + lq * 4) = outp;
    }
  }
}

// ---------------- seg + pool fused: 16 bins, 1-wave blocks ----------------
__global__ __launch_bounds__(64) void k_segpool(const bf16* __restrict__ h,
    const bf16* __restrict__ op, const float* __restrict__ segw,
    const float* __restrict__ rw, float* __restrict__ part) {
  int lp = blockIdx.x, b = blockIdx.y, ch = blockIdx.z;
  int t = threadIdx.x;
  int c0 = t * 2;
  float w0 = segw[ch * 128 + c0], w1 = segw[ch * 128 + c0 + 1];
  float rwv = rw[b * 8 + ch];
  float a0 = 0.f, a1 = 0.f;
  for (int l = 0; l < 36; l++) {
    int row = b * Lq + lp * 36 + l;
    const bf16* oprow = op + (long)ch * ROWS * CW + (long)row * CW;
    bf16x2 yv = *(const bf16x2*)(oprow + c0);
    float y0 = (float)yv[0], y1 = (float)yv[1];
    float ss = y0 * y0 + y1 * y1;
    #pragma unroll
    for (int m = 1; m < 64; m <<= 1) ss += __shfl_xor(ss, m);
    float r = rsqrtf(ss * (1.f / 128.f) + EPS);
    bf16x2 hv = *(const bf16x2*)(h + (long)row * WIDTH + ch * 128 + c0);
    a0 += ((float)hv[0] + y0 * r * w0) * rwv;
    a1 += ((float)hv[1] + y1 * r * w1) * rwv;
  }
  float* dst = part + ((long)b * 16 + lp) * 1024 + ch * 128 + c0;
  dst[0] = a0; dst[1] = a1;
}

// ---------------- head (reads 16 pool partials) ----------------
__global__ __launch_bounds__(256) void k_head(const float* __restrict__ part,
    const float* __restrict__ hw, const float* __restrict__ hb, float* __restrict__ out) {
  __shared__ float pool[1024];
  __shared__ float red[256];
  int b = blockIdx.x, t = threadIdx.x;
  for (int c = t; c < 1024; c += 256) {
    float a = 0.f;
    #pragma unroll
    for (int lp = 0; lp < 16; lp++) a += part[((long)b * 16 + lp) * 1024 + c];
    pool[c] = a * (1.f / 576.f);
  }
  __syncthreads();
  int j = t & 15, pt = t >> 4;
  float acc = 0.f;
  if (j < 10)
    for (int c = pt * 64; c < pt * 64 + 64; c++)
      acc += pool[c] * hw[c * 10 + j];
  red[t] = acc;
  __syncthreads();
  if (t < 10) {
    float a = hb[t];
    for (int p = 0; p < 16; p++) a += red[p * 16 + t];
    out[b * 10 + t] = a;
  }
}

// ---------------- launcher ----------------
extern "C" void kernel_launch(void* const* d_in, const int* in_sizes, int n_in,
                              void* d_out, int out_size, void* d_ws, size_t ws_size,
                              hipStream_t stream) {
  const float* x          = (const float*)d_in[0];
  const float* pixel_embed= (const float*)d_in[2];
  const float* freq_h     = (const float*)d_in[3];
  const float* freq_w     = (const float*)d_in[4];
  const float* phase_h    = (const float*)d_in[5];
  const float* phase_w    = (const float*)d_in[6];
  const float* pos_proj_w = (const float*)d_in[7];
  const float* pos_proj_b = (const float*)d_in[8];
  const float* embed_norm = (const float*)d_in[9];
  const float* se_w1      = (const float*)d_in[10];
  const float* se_b1      = (const float*)d_in[11];
  const float* se_w2      = (const float*)d_in[12];
  const float* se_b2      = (const float*)d_in[13];
  const float* mix_norm   = (const float*)d_in[14];
  const float* mlp_w1     = (const float*)d_in[15];
  const float* mlp_b1     = (const float*)d_in[16];
  const float* mlp_w2     = (const float*)d_in[17];
  const float* mlp_b2     = (const float*)d_in[18];
  const float* mlp_norm   = (const float*)d_in[19];
  const float* router_w   = (const float*)d_in[20];
  const float* router_b   = (const float*)d_in[21];
  const float* qkv_w      = (const float*)d_in[22];
  const float* qkv_b      = (const float*)d_in[23];
  const float* q_norm_w   = (const float*)d_in[24];
  const float* k_norm_w   = (const float*)d_in[25];
  const float* head_norm_w= (const float*)d_in[26];
  const float* lam_q1     = (const float*)d_in[27];
  const float* lam_k1     = (const float*)d_in[28];
  const float* lam_q2     = (const float*)d_in[29];
  const float* lam_k2     = (const float*)d_in[30];
  const float* out_w      = (const float*)d_in[31];
  const float* out_b      = (const float*)d_in[32];
  const float* seg_norm_w = (const float*)d_in[33];
  const float* head_w     = (const float*)d_in[34];
  const float* head_b     = (const float*)d_in[35];

  char* W = (char*)d_ws;
  bf16*  HB    = (bf16*)(W + B_HB);
  bf16*  G2B   = (bf16*)(W + B_G2B);
  float* POS   = (float*)(W + B_G2B);      // POS lives in G2B region (dead until MLP)
  bf16*  ENCB  = (bf16*)(W + B_ENCB);
  bf16*  POSWT = (bf16*)(W + B_POSWT);
  bf16*  QKVWT = (bf16*)(W + B_QKVWT);
  bf16*  OWT   = (bf16*)(W + B_OWT);
  float* SE    = (float*)(W + B_SE);
  float* T1    = (float*)(W + B_T1);
  float* MP    = (float*)(W + B_MP);
  float* RW    = (float*)(W + B_RW);
  float* LAM   = (float*)(W + B_LAM);
  char*  P     = W + B_POOL;
  bf16*  W1T   = (bf16*)P;
  bf16*  W2T   = (bf16*)(P + 8388608);
  bf16*  HID   = (bf16*)(P + 16777216);
  bf16*  PARTS = (bf16*)(P + 16777216 + 37748736);   // after full-width HID
  bf16*  QKV   = (bf16*)P;
  bf16*  DC    = (bf16*)(P + 28311552);
  float* out   = (float*)d_out;
  const int tier = (ws_size >= WS_BIG3) ? 3 : (ws_size >= WS_BIG2) ? 2
                 : (ws_size >= WS_BIG) ? 1 : 0;

  // 0. all weight casts in one dispatch
  k_tcast_all<<<8832, 256, 0, stream>>>(mlp_w1, mlp_w2, pos_proj_w, qkv_w, out_w,
                                        W1T, W2T, POSWT, QKVWT, OWT);
  // 1. positional encoding + projection (POS f32 in G2B region)
  k_enc_b<<<288, 256, 0, stream>>>(freq_h, freq_w, phase_h, phase_w, ENCB);
  gemm64<0, 0, 0, 0><<<dim3(8, 10, 1), 256, 0, stream>>>(
      ENCB, 128, 0, POSWT, 128, 0, pos_proj_b, 0, POS, 1024, 0, 640, 1024, 128,
      nullptr, nullptr);
  // 2. embed + rmsnorm -> bf16 h
  k_embed<<<ROWS, 256, 0, stream>>>(x, pixel_embed, POS, embed_norm, HB);
  // 3. SE gate
  k_meanl_p<<<dim3(16, 8), 256, 0, stream>>>(HB, MP);
  k_se1<<<dim3(32, 8), 256, 0, stream>>>(MP, se_w1, se_b1, T1);
  k_se2<<<dim3(32, 8), 256, 0, stream>>>(T1, se_w2, se_b2, SE);
  k_mix_b<<<ROWS, 256, 0, stream>>>(HB, SE, mix_norm);
  // 4. MLP
  if (tier >= 1) {
    // gemm1: single GEMM M=4608 N=4096 K=1024, XCD-pinned groups (m, n-half)
    gemm_bt<1, 1, 1><<<1152, 256, 0, stream>>>(
        HB, 1024, 0, W1T, 1024, 0, mlp_b1, 0,
        HID, 4096, 0, 4608, 4096, 1024);
    if (tier == 3) {
      // gemm2: 4-way K-split, XCD-pinned (m,z) groups, 1152 blocks -> 4.5 blk/CU
      gemm_bt<0, 1, 2><<<1152, 256, 0, stream>>>(
          HID, 4096, 1024, W2T, 4096, 1024, nullptr, 0,
          PARTS, 1024, PSTRIDE, 4608, 1024, 1024);
      k_addnorm4<<<ROWS, 256, 0, stream>>>(HB, PARTS, mlp_b2, mlp_norm);
    } else if (tier == 2) {
      // gemm2: 2-way K-split, XCD-pinned, partials in G2B + PARTS[0]
      gemm_bt<0, 1, 2><<<576, 256, 0, stream>>>(
          HID, 4096, 2048, W2T, 4096, 2048, nullptr, 0,
          G2B, 1024, (long)(PARTS - G2B), 4608, 1024, 2048);
      k_addnorm2<<<ROWS, 256, 0, stream>>>(HB, G2B, PARTS, mlp_b2, mlp_norm);
    } else {
      gemm64<0, 1, 0, 0><<<dim3(8, 72, 1), 256, 0, stream>>>(
          HID, 4096, 0, W2T, 4096, 0, mlp_b2, 0,
          G2B, 1024, 0, 4608, 1024, 4096, nullptr, nullptr);
      k_addnorm_b<<<ROWS, 256, 0, stream>>>(HB, G2B, mlp_norm);
    }
  } else {
    gemm_bt<1, 1, 0><<<dim3(16, 36, 1), 256, 0, stream>>>(
        HB, 1024, 0, W1T, 1024, 0, mlp_b1, 0, HID, 2048, 0, 4608, 2048, 1024);
    gemm64<0, 1, 0, 0><<<dim3(8, 72, 1), 256, 0, stream>>>(
        HID, 2048, 0, W2T, 4096, 0, mlp_b2, 0, G2B, 1024, 0, 4608, 1024, 2048,
        nullptr, nullptr);
    gemm_bt<1, 1, 0><<<dim3(16, 36, 1), 256, 0, stream>>>(
        HB, 1024, 0, W1T + 2048L * 1024, 1024, 0, mlp_b1 + 2048, 0, HID, 2048, 0,
        4608, 2048, 1024);
    gemm64<0, 1, 1, 0><<<dim3(8, 72, 1), 256, 0, stream>>>(
        HID, 2048, 0, W2T + 2048, 4096, 0, nullptr, 0, G2B, 1024, 0,
        4608, 1024, 2048, nullptr, nullptr);
    k_addnorm_b<<<ROWS, 256, 0, stream>>>(HB, G2B, mlp_norm);
  }
  // 5. router + lambdas
  k_meanl_p<<<dim3(16, 8), 256, 0, stream>>>(HB, MP);
  k_router<<<8, 256, 0, stream>>>(MP, router_w, router_b,
                                  lam_q1, lam_k1, lam_q2, lam_k2, RW, LAM);
  // 6. qkv-proj with fused silu + Q/K rmsnorm (+ Q prescale) in epilogue
  gemm64<1, 1, 0, 1><<<dim3(3, 72, 8), 256, 0, stream>>>(
      HB, 1024, CW, QKVWT, 128, 384 * 128, qkv_b, 384,
      QKV, 384, (long)ROWS * 384, ROWS, 384, 128, q_norm_w, k_norm_w);
  // 7. attention (prenormed), out-proj in-place on DC
  k_attn_mfma<<<dim3(64, 2, 8), 256, 0, stream>>>(QKV, LAM, head_norm_w, DC);
  gemm64<1, 1, 0, 0><<<dim3(1, 72, 8), 256, 0, stream>>>(
      DC, 128, (long)ROWS * 128, OWT, 128, 128 * 128, out_b, 128,
      DC, 128, (long)ROWS * 128, ROWS, 128, 128, nullptr, nullptr);
  // 8. seg + pool fused -> 16 partials; head folds the final reduce
  k_segpool<<<dim3(16, 8, 8), 64, 0, stream>>>(HB, DC, seg_norm_w, RW, MP);
  k_head<<<8, 256, 0, stream>>>(MP, head_w, head_b, out);
}